// Round 1
// baseline (1255.496 us; speedup 1.0000x reference)
//
#include <hip/hip_runtime.h>
#include <hip/hip_bf16.h>
#include <math.h>
#include <stdint.h>

#define N_NODES 50000
#define N_EDGES 800000
#define E_TOT   (N_EDGES + N_NODES)   // 850000 with self loops
#define IN_CH   128
#define HID     64
#define NHEAD   8
#define C       512                   // NHEAD*HID
#define NEG_SLOPE 0.2f
#define BN_EPS    1e-5f
#define SM_EPS    1e-16f

__device__ __forceinline__ float lrelu(float x){ return x > 0.f ? x : NEG_SLOPE * x; }
__device__ __forceinline__ float elu(float x){ return x > 0.f ? x : expm1f(x); }

// ---------------- edge dtype probe + extraction ----------------
__global__ void k_detect(const int* __restrict__ ei, int* flag){
  if (threadIdx.x == 0 && blockIdx.x == 0) {
    int f = 1;
    for (int i = 0; i < 32; i++) if (ei[2*i + 1] != 0) f = 0;  // int64 => high words 0
    *flag = f;
  }
}
__global__ void k_extract(const int* __restrict__ ei, const int* __restrict__ flag,
                          int* __restrict__ src32, int* __restrict__ dst32){
  int e = blockIdx.x * 256 + threadIdx.x;
  if (e >= N_EDGES) return;
  if (*flag) {
    const long long* e64 = (const long long*)ei;
    src32[e] = (int)e64[e];
    dst32[e] = (int)e64[(size_t)N_EDGES + e];
  } else {
    src32[e] = ei[e];
    dst32[e] = ei[N_EDGES + e];
  }
}

// ---------------- CSR build ----------------
__global__ void k_init_counts(int* counts){
  int i = blockIdx.x * 256 + threadIdx.x;
  if (i < N_NODES) counts[i] = 1;            // self loop
}
__global__ void k_count(const int* __restrict__ dst, int* counts){
  int e = blockIdx.x * 256 + threadIdx.x;
  if (e < N_EDGES) atomicAdd(&counts[dst[e]], 1);
}
__global__ void k_scan(const int* __restrict__ counts, int* __restrict__ off, int* __restrict__ cursor){
  __shared__ int s[1024];
  __shared__ int carry_s;
  if (threadIdx.x == 0) carry_s = 0;
  __syncthreads();
  for (int base = 0; base < N_NODES; base += 1024) {
    int i = base + threadIdx.x;
    int v = (i < N_NODES) ? counts[i] : 0;
    s[threadIdx.x] = v;
    __syncthreads();
    for (int d = 1; d < 1024; d <<= 1) {
      int t = (threadIdx.x >= d) ? s[threadIdx.x - d] : 0;
      __syncthreads();
      s[threadIdx.x] += t;
      __syncthreads();
    }
    int excl = carry_s + ((threadIdx.x > 0) ? s[threadIdx.x - 1] : 0);
    if (i < N_NODES) { off[i] = excl; cursor[i] = excl; }
    __syncthreads();
    if (threadIdx.x == 0) carry_s += s[1023];
    __syncthreads();
  }
  if (threadIdx.x == 0) off[N_NODES] = carry_s;
}
__global__ void k_scatter_self(int* cursor, int* __restrict__ csr_src){
  int i = blockIdx.x * 256 + threadIdx.x;
  if (i < N_NODES) { int p = atomicAdd(&cursor[i], 1); csr_src[p] = i; }
}
__global__ void k_scatter_edges(const int* __restrict__ src, const int* __restrict__ dst,
                                int* cursor, int* __restrict__ csr_src){
  int e = blockIdx.x * 256 + threadIdx.x;
  if (e < N_EDGES) { int d = dst[e]; int p = atomicAdd(&cursor[d], 1); csr_src[p] = src[e]; }
}

// ---------------- GEMM0: [N,128] @ W0[h][128][64] -> H[N, h*64+c] ----------------
__global__ __launch_bounds__(256) void k_gemm0(const float* __restrict__ X,
                                               const float* __restrict__ W,
                                               float* __restrict__ Hout){
  __shared__ float As[64][68];
  __shared__ float Bs[64][68];
  int r0 = blockIdx.x * 64;
  int h  = blockIdx.y;
  int tid = threadIdx.x;
  int tx = tid & 15, ty = tid >> 4;
  float acc[4][4] = {};
  for (int kk = 0; kk < IN_CH; kk += 64) {
#pragma unroll
    for (int i = 0; i < 4; i++) {
      int idx = tid + i * 256;
      int r = idx >> 4, kv = (idx & 15) * 4;
      float4 v = make_float4(0.f, 0.f, 0.f, 0.f);
      if (r0 + r < N_NODES)
        v = *reinterpret_cast<const float4*>(&X[(size_t)(r0 + r) * IN_CH + kk + kv]);
      As[r][kv] = v.x; As[r][kv+1] = v.y; As[r][kv+2] = v.z; As[r][kv+3] = v.w;
    }
#pragma unroll
    for (int i = 0; i < 4; i++) {
      int idx = tid + i * 256;
      int k = idx >> 4, cv = (idx & 15) * 4;
      float4 v = *reinterpret_cast<const float4*>(&W[((size_t)h * IN_CH + kk + k) * HID + cv]);
      Bs[k][cv] = v.x; Bs[k][cv+1] = v.y; Bs[k][cv+2] = v.z; Bs[k][cv+3] = v.w;
    }
    __syncthreads();
#pragma unroll
    for (int k = 0; k < 64; k++) {
      float a[4], b[4];
#pragma unroll
      for (int i = 0; i < 4; i++) a[i] = As[ty*4 + i][k];
#pragma unroll
      for (int j = 0; j < 4; j++) b[j] = Bs[k][tx*4 + j];
#pragma unroll
      for (int i = 0; i < 4; i++)
#pragma unroll
        for (int j = 0; j < 4; j++) acc[i][j] += a[i] * b[j];
    }
    __syncthreads();
  }
#pragma unroll
  for (int i = 0; i < 4; i++) {
    int r = r0 + ty*4 + i;
    if (r < N_NODES) {
#pragma unroll
      for (int j = 0; j < 4; j++)
        Hout[(size_t)r * C + h * HID + tx*4 + j] = acc[i][j];
    }
  }
}

// ---------------- per-node attention scores s_src/s_dst ----------------
__global__ __launch_bounds__(256) void k_compute_s(const float* __restrict__ Hm,
                                                   const float* __restrict__ a_src,
                                                   const float* __restrict__ a_dst,
                                                   float* __restrict__ s_src,
                                                   float* __restrict__ s_dst){
  int wave = threadIdx.x >> 6, lane = threadIdx.x & 63;
  int n = blockIdx.x * 4 + wave;
  if (n >= N_NODES) return;
#pragma unroll
  for (int h = 0; h < NHEAD; h++) {
    float v  = Hm[(size_t)n * C + h * HID + lane];
    float ps = v * a_src[h * HID + lane];
    float pd = v * a_dst[h * HID + lane];
#pragma unroll
    for (int o = 32; o; o >>= 1) { ps += __shfl_xor(ps, o, 64); pd += __shfl_xor(pd, o, 64); }
    if (lane == 0) { s_src[n * NHEAD + h] = ps; s_dst[n * NHEAD + h] = pd; }
  }
}

// ---------------- per-node softmax + aggregation (1 wave / node) ----------------
__global__ __launch_bounds__(256) void k_aggregate(const float* __restrict__ Hin,
                                                   const float* __restrict__ s_src,
                                                   const float* __restrict__ s_dst,
                                                   const int* __restrict__ off,
                                                   const int* __restrict__ csr,
                                                   const float* __restrict__ bias,
                                                   float* __restrict__ Hout){
  int wave = threadIdx.x >> 6, lane = threadIdx.x & 63;
  int n = blockIdx.x * 4 + wave;
  if (n >= N_NODES) return;
  int e0 = off[n], e1 = off[n + 1];
  int deg = e1 - e0;

  float sd[NHEAD];
#pragma unroll
  for (int h = 0; h < NHEAD; h++) sd[h] = s_dst[n * NHEAD + h];

  // pass 1: segment max
  float m[NHEAD];
#pragma unroll
  for (int h = 0; h < NHEAD; h++) m[h] = -1e30f;
  for (int base = 0; base < deg; base += 64) {
    int e = base + lane;
    if (e < deg) {
      int s = csr[e0 + e];
#pragma unroll
      for (int h = 0; h < NHEAD; h++)
        m[h] = fmaxf(m[h], lrelu(s_src[s * NHEAD + h] + sd[h]));
    }
  }
#pragma unroll
  for (int h = 0; h < NHEAD; h++)
#pragma unroll
    for (int o = 32; o; o >>= 1) m[h] = fmaxf(m[h], __shfl_xor(m[h], o, 64));

  // pass 2: denominator
  float dn[NHEAD] = {};
  for (int base = 0; base < deg; base += 64) {
    int e = base + lane;
    if (e < deg) {
      int s = csr[e0 + e];
#pragma unroll
      for (int h = 0; h < NHEAD; h++)
        dn[h] += __expf(lrelu(s_src[s * NHEAD + h] + sd[h]) - m[h]);
    }
  }
#pragma unroll
  for (int h = 0; h < NHEAD; h++) {
#pragma unroll
    for (int o = 32; o; o >>= 1) dn[h] += __shfl_xor(dn[h], o, 64);
  }
  float inv[NHEAD];
#pragma unroll
  for (int h = 0; h < NHEAD; h++) inv[h] = 1.f / (dn[h] + SM_EPS);

  // pass 3: weighted gather; lane = channel within head
  float acc[NHEAD] = {};
  for (int base = 0; base < deg; base += 64) {
    int e = base + lane;
    int cnt = min(64, deg - base);
    int s_reg = 0;
    float alpha[NHEAD];
#pragma unroll
    for (int h = 0; h < NHEAD; h++) alpha[h] = 0.f;
    if (e < deg) {
      s_reg = csr[e0 + e];
#pragma unroll
      for (int h = 0; h < NHEAD; h++)
        alpha[h] = __expf(lrelu(s_src[s_reg * NHEAD + h] + sd[h]) - m[h]) * inv[h];
    }
    for (int j = 0; j < cnt; j++) {
      int s = __shfl(s_reg, j, 64);
      const float* row = Hin + (size_t)s * C;
#pragma unroll
      for (int h = 0; h < NHEAD; h++) {
        float a = __shfl(alpha[h], j, 64);
        acc[h] += a * row[h * HID + lane];
      }
    }
  }
#pragma unroll
  for (int h = 0; h < NHEAD; h++)
    Hout[(size_t)n * C + h * HID + lane] = acc[h] + bias[h * HID + lane];
}

// ---------------- BatchNorm stats ----------------
__global__ void k_zero_stats(float* stats){ stats[threadIdx.x] = 0.f; }  // 1024 threads
__global__ __launch_bounds__(256) void k_bn_stats(const float* __restrict__ Hm, float* __restrict__ stats){
  int c = threadIdx.x;   // channels c and c+256
  float s0 = 0.f, q0 = 0.f, s1 = 0.f, q1 = 0.f;
  for (int r = blockIdx.x; r < N_NODES; r += gridDim.x) {
    float v0 = Hm[(size_t)r * C + c];
    float v1 = Hm[(size_t)r * C + c + 256];
    s0 += v0; q0 += v0 * v0; s1 += v1; q1 += v1 * v1;
  }
  atomicAdd(&stats[c], s0);
  atomicAdd(&stats[c + 256], s1);
  atomicAdd(&stats[C + c], q0);
  atomicAdd(&stats[C + c + 256], q1);
}
__global__ void k_bn_finalize(const float* __restrict__ stats, const float* __restrict__ gamma,
                              const float* __restrict__ beta, float* __restrict__ scale,
                              float* __restrict__ shift){
  int c = threadIdx.x;  // 512 threads
  float mean = stats[c] * (1.f / N_NODES);
  float var  = stats[C + c] * (1.f / N_NODES) - mean * mean;
  float sc = gamma[c] * rsqrtf(var + BN_EPS);
  scale[c] = sc;
  shift[c] = beta[c] - mean * sc;
}

// ---------------- GEMM1 (in place, per head): elu(bn(H)) @ W1[h] ----------------
__global__ __launch_bounds__(256) void k_gemm1(float* __restrict__ Hm,
                                               const float* __restrict__ W,
                                               const float* __restrict__ scale,
                                               const float* __restrict__ shift){
  __shared__ float As[64][68];
  __shared__ float Bs[64][68];
  int r0 = blockIdx.x * 64;
  int h  = blockIdx.y;
  int tid = threadIdx.x;
  int tx = tid & 15, ty = tid >> 4;
#pragma unroll
  for (int i = 0; i < 4; i++) {
    int idx = tid + i * 256;
    int r = idx >> 4, kv = (idx & 15) * 4;
    float4 v = make_float4(0.f, 0.f, 0.f, 0.f);
    if (r0 + r < N_NODES)
      v = *reinterpret_cast<const float4*>(&Hm[(size_t)(r0 + r) * C + h * HID + kv]);
    float4 sc = *reinterpret_cast<const float4*>(&scale[h * HID + kv]);
    float4 sh = *reinterpret_cast<const float4*>(&shift[h * HID + kv]);
    As[r][kv]   = elu(sc.x * v.x + sh.x);
    As[r][kv+1] = elu(sc.y * v.y + sh.y);
    As[r][kv+2] = elu(sc.z * v.z + sh.z);
    As[r][kv+3] = elu(sc.w * v.w + sh.w);
  }
#pragma unroll
  for (int i = 0; i < 4; i++) {
    int idx = tid + i * 256;
    int k = idx >> 4, cv = (idx & 15) * 4;
    float4 v = *reinterpret_cast<const float4*>(&W[((size_t)h * HID + k) * HID + cv]);
    Bs[k][cv] = v.x; Bs[k][cv+1] = v.y; Bs[k][cv+2] = v.z; Bs[k][cv+3] = v.w;
  }
  __syncthreads();
  float acc[4][4] = {};
#pragma unroll
  for (int k = 0; k < 64; k++) {
    float a[4], b[4];
#pragma unroll
    for (int i = 0; i < 4; i++) a[i] = As[ty*4 + i][k];
#pragma unroll
    for (int j = 0; j < 4; j++) b[j] = Bs[k][tx*4 + j];
#pragma unroll
    for (int i = 0; i < 4; i++)
#pragma unroll
      for (int j = 0; j < 4; j++) acc[i][j] += a[i] * b[j];
  }
  __syncthreads();
#pragma unroll
  for (int i = 0; i < 4; i++) {
    int r = r0 + ty*4 + i;
    if (r < N_NODES) {
#pragma unroll
      for (int j = 0; j < 4; j++)
        Hm[(size_t)r * C + h * HID + tx*4 + j] = acc[i][j];
    }
  }
}

// ---------------- final: out = elu(bn(H)) @ Wc + bc ----------------
__global__ __launch_bounds__(256) void k_final(const float* __restrict__ Hm,
                                               const float* __restrict__ scale,
                                               const float* __restrict__ shift,
                                               const float* __restrict__ Wc,
                                               const float* __restrict__ bc,
                                               float* __restrict__ out){
  int wave = threadIdx.x >> 6, lane = threadIdx.x & 63;
  int n = blockIdx.x * 4 + wave;
  if (n >= N_NODES) return;
  float a0 = 0.f, a1 = 0.f;
#pragma unroll
  for (int h = 0; h < NHEAD; h++) {
    int ch = h * HID + lane;
    float v = Hm[(size_t)n * C + ch];
    v = scale[ch] * v + shift[ch];
    v = elu(v);
    a0 += v * Wc[ch * 2 + 0];
    a1 += v * Wc[ch * 2 + 1];
  }
#pragma unroll
  for (int o = 32; o; o >>= 1) { a0 += __shfl_xor(a0, o, 64); a1 += __shfl_xor(a1, o, 64); }
  if (lane == 0) { out[n * 2 + 0] = a0 + bc[0]; out[n * 2 + 1] = a1 + bc[1]; }
}

extern "C" void kernel_launch(void* const* d_in, const int* in_sizes, int n_in,
                              void* d_out, int out_size, void* d_ws, size_t ws_size,
                              hipStream_t stream) {
  const float* x      = (const float*)d_in[0];
  const int*   ei     = (const int*)d_in[1];
  const float* W0     = (const float*)d_in[2];
  const float* a_src0 = (const float*)d_in[3];
  const float* a_dst0 = (const float*)d_in[4];
  const float* b0     = (const float*)d_in[5];
  const float* gamma0 = (const float*)d_in[6];
  const float* beta0  = (const float*)d_in[7];
  const float* W1     = (const float*)d_in[8];
  const float* a_src1 = (const float*)d_in[9];
  const float* a_dst1 = (const float*)d_in[10];
  const float* b1     = (const float*)d_in[11];
  const float* gamma1 = (const float*)d_in[12];
  const float* beta1  = (const float*)d_in[13];
  const float* Wc     = (const float*)d_in[14];
  const float* bc     = (const float*)d_in[15];
  float* out = (float*)d_out;

  char* ws = (char*)d_ws;
  size_t o = 0;
  auto alloc = [&](size_t bytes) { char* p = ws + o; o = (o + bytes + 255) & ~(size_t)255; return p; };
  int*   flag    = (int*)  alloc(4);
  int*   src32   = (int*)  alloc((size_t)N_EDGES * 4);
  int*   dst32   = (int*)  alloc((size_t)N_EDGES * 4);
  int*   counts  = (int*)  alloc((size_t)N_NODES * 4);
  int*   off     = (int*)  alloc((size_t)(N_NODES + 1) * 4);
  int*   cursor  = (int*)  alloc((size_t)N_NODES * 4);
  int*   csr     = (int*)  alloc((size_t)E_TOT * 4);
  float* s_src   = (float*)alloc((size_t)N_NODES * NHEAD * 4);
  float* s_dst   = (float*)alloc((size_t)N_NODES * NHEAD * 4);
  float* stats   = (float*)alloc(1024 * 4);
  float* scale   = (float*)alloc(C * 4);
  float* shift   = (float*)alloc(C * 4);
  float* h_a     = (float*)alloc((size_t)N_NODES * C * 4);
  float* h_b     = (float*)alloc((size_t)N_NODES * C * 4);

  const int GE = (N_EDGES + 255) / 256;      // 3125
  const int GN = (N_NODES + 255) / 256;      // 196
  const int GW = (N_NODES + 3) / 4;          // 12500 (4 waves/block, 1 node/wave)
  const int GR = (N_NODES + 63) / 64;        // 782 row tiles

  // edges -> int32, CSR by dst (with self loops)
  k_detect<<<1, 64, 0, stream>>>(ei, flag);
  k_extract<<<GE, 256, 0, stream>>>(ei, flag, src32, dst32);
  k_init_counts<<<GN, 256, 0, stream>>>(counts);
  k_count<<<GE, 256, 0, stream>>>(dst32, counts);
  k_scan<<<1, 1024, 0, stream>>>(counts, off, cursor);
  k_scatter_self<<<GN, 256, 0, stream>>>(cursor, csr);
  k_scatter_edges<<<GE, 256, 0, stream>>>(src32, dst32, cursor, csr);

  // ----- layer 0 -----
  k_gemm0<<<dim3(GR, NHEAD), 256, 0, stream>>>(x, W0, h_a);
  k_compute_s<<<GW, 256, 0, stream>>>(h_a, a_src0, a_dst0, s_src, s_dst);
  k_aggregate<<<GW, 256, 0, stream>>>(h_a, s_src, s_dst, off, csr, b0, h_b);
  k_zero_stats<<<1, 1024, 0, stream>>>(stats);
  k_bn_stats<<<256, 256, 0, stream>>>(h_b, stats);
  k_bn_finalize<<<1, 512, 0, stream>>>(stats, gamma0, beta0, scale, shift);

  // ----- layer 1 (BN0+ELU fused into GEMM1 load; GEMM1 in place on h_b) -----
  k_gemm1<<<dim3(GR, NHEAD), 256, 0, stream>>>(h_b, W1, scale, shift);
  k_compute_s<<<GW, 256, 0, stream>>>(h_b, a_src1, a_dst1, s_src, s_dst);
  k_aggregate<<<GW, 256, 0, stream>>>(h_b, s_src, s_dst, off, csr, b1, h_a);
  k_zero_stats<<<1, 1024, 0, stream>>>(stats);
  k_bn_stats<<<256, 256, 0, stream>>>(h_a, stats);
  k_bn_finalize<<<1, 512, 0, stream>>>(stats, gamma1, beta1, scale, shift);

  // ----- classifier (BN1+ELU fused) -----
  k_final<<<GW, 256, 0, stream>>>(h_a, scale, shift, Wc, bc, out);
}

// Round 2
// 829.133 us; speedup vs baseline: 1.5142x; 1.5142x over previous
//
#include <hip/hip_runtime.h>
#include <hip/hip_bf16.h>
#include <math.h>
#include <stdint.h>

#define N_NODES 50000
#define N_EDGES 800000
#define E_TOT   (N_EDGES + N_NODES)   // 850000 with self loops
#define IN_CH   128
#define HID     64
#define NHEAD   8
#define C       512                   // NHEAD*HID
#define NEG_SLOPE 0.2f
#define BN_EPS    1e-5f
#define SM_EPS    1e-16f
#define SCAN_B    196                 // ceil(N_NODES/256)

__device__ __forceinline__ float lrelu(float x){ return x > 0.f ? x : NEG_SLOPE * x; }
__device__ __forceinline__ float elu(float x){ return x > 0.f ? x : expm1f(x); }
__device__ __forceinline__ float bflo(unsigned u){ return __uint_as_float(u << 16); }
__device__ __forceinline__ float bfhi(unsigned u){ return __uint_as_float(u & 0xffff0000u); }
__device__ __forceinline__ unsigned short f2bf(float f){
  unsigned u = __float_as_uint(f);
  unsigned r = u + 0x7fffu + ((u >> 16) & 1u);   // RNE
  return (unsigned short)(r >> 16);
}

// ---------------- edge dtype probe + extraction (+count fused) ----------------
__global__ void k_detect(const int* __restrict__ ei, int* flag){
  if (threadIdx.x == 0 && blockIdx.x == 0) {
    int f = 1;
    for (int i = 0; i < 32; i++) if (ei[2*i + 1] != 0) f = 0;  // int64 => high words 0
    *flag = f;
  }
}
__global__ void k_init_counts(int* counts){
  int i = blockIdx.x * 256 + threadIdx.x;
  if (i < N_NODES) counts[i] = 1;            // self loop
}
__global__ void k_extract_count(const int* __restrict__ ei, const int* __restrict__ flag,
                                int* __restrict__ src32, int* __restrict__ dst32,
                                int* counts){
  int e = blockIdx.x * 256 + threadIdx.x;
  if (e >= N_EDGES) return;
  int s, d;
  if (*flag) {
    const long long* e64 = (const long long*)ei;
    s = (int)e64[e];
    d = (int)e64[(size_t)N_EDGES + e];
  } else {
    s = ei[e];
    d = ei[N_EDGES + e];
  }
  src32[e] = s; dst32[e] = d;
  atomicAdd(&counts[d], 1);
}

// ---------------- multi-block exclusive scan ----------------
__global__ void k_scan1(const int* __restrict__ counts, int* __restrict__ excl, int* __restrict__ bsum){
  __shared__ int s[256];
  int tid = threadIdx.x;
  int i = blockIdx.x * 256 + tid;
  int v = (i < N_NODES) ? counts[i] : 0;
  s[tid] = v; __syncthreads();
#pragma unroll
  for (int d = 1; d < 256; d <<= 1) {
    int t = (tid >= d) ? s[tid - d] : 0;
    __syncthreads(); s[tid] += t; __syncthreads();
  }
  if (i < N_NODES) excl[i] = s[tid] - v;
  if (tid == 255) bsum[blockIdx.x] = s[255];
}
__global__ void k_scan2(int* bsum){
  __shared__ int s[256];
  int tid = threadIdx.x;
  int v = (tid < SCAN_B) ? bsum[tid] : 0;
  s[tid] = v; __syncthreads();
#pragma unroll
  for (int d = 1; d < 256; d <<= 1) {
    int t = (tid >= d) ? s[tid - d] : 0;
    __syncthreads(); s[tid] += t; __syncthreads();
  }
  if (tid < SCAN_B) bsum[tid] = s[tid] - v;
}
__global__ void k_scan3(const int* __restrict__ excl, const int* __restrict__ bsum,
                        int* __restrict__ off, int* __restrict__ cursor){
  int i = blockIdx.x * 256 + threadIdx.x;
  if (i < N_NODES) { int o = excl[i] + bsum[blockIdx.x]; off[i] = o; cursor[i] = o; }
  if (i == 0) off[N_NODES] = E_TOT;
}
__global__ void k_scatter_self(int* cursor, int* __restrict__ csr_src){
  int i = blockIdx.x * 256 + threadIdx.x;
  if (i < N_NODES) { int p = atomicAdd(&cursor[i], 1); csr_src[p] = i; }
}
__global__ void k_scatter_edges(const int* __restrict__ src, const int* __restrict__ dst,
                                int* cursor, int* __restrict__ csr_src){
  int e = blockIdx.x * 256 + threadIdx.x;
  if (e < N_EDGES) { int d = dst[e]; int p = atomicAdd(&cursor[d], 1); csr_src[p] = src[e]; }
}

// ---------------- GEMM0: [N,128] @ W0[h][128][64] -> H16 bf16 + s_src/s_dst ----------------
__global__ __launch_bounds__(256) void k_gemm0(const float* __restrict__ X,
                                               const float* __restrict__ W,
                                               const float* __restrict__ a_src,
                                               const float* __restrict__ a_dst,
                                               unsigned short* __restrict__ H16,
                                               float* __restrict__ s_src,
                                               float* __restrict__ s_dst){
  __shared__ float As[64][68];
  __shared__ float Bs[64][68];
  __shared__ float Ps[64][16];
  __shared__ float Pd[64][16];
  int r0 = blockIdx.x * 64;
  int h  = blockIdx.y;
  int tid = threadIdx.x;
  int tx = tid & 15, ty = tid >> 4;
  float acc[4][4] = {};
  for (int kk = 0; kk < IN_CH; kk += 64) {
#pragma unroll
    for (int i = 0; i < 4; i++) {
      int idx = tid + i * 256;
      int r = idx >> 4, kv = (idx & 15) * 4;
      float4 v = make_float4(0.f, 0.f, 0.f, 0.f);
      if (r0 + r < N_NODES)
        v = *reinterpret_cast<const float4*>(&X[(size_t)(r0 + r) * IN_CH + kk + kv]);
      As[r][kv] = v.x; As[r][kv+1] = v.y; As[r][kv+2] = v.z; As[r][kv+3] = v.w;
    }
#pragma unroll
    for (int i = 0; i < 4; i++) {
      int idx = tid + i * 256;
      int k = idx >> 4, cv = (idx & 15) * 4;
      float4 v = *reinterpret_cast<const float4*>(&W[((size_t)h * IN_CH + kk + k) * HID + cv]);
      Bs[k][cv] = v.x; Bs[k][cv+1] = v.y; Bs[k][cv+2] = v.z; Bs[k][cv+3] = v.w;
    }
    __syncthreads();
#pragma unroll
    for (int k = 0; k < 64; k++) {
      float a[4], b[4];
#pragma unroll
      for (int i = 0; i < 4; i++) a[i] = As[ty*4 + i][k];
#pragma unroll
      for (int j = 0; j < 4; j++) b[j] = Bs[k][tx*4 + j];
#pragma unroll
      for (int i = 0; i < 4; i++)
#pragma unroll
        for (int j = 0; j < 4; j++) acc[i][j] += a[i] * b[j];
    }
    __syncthreads();
  }
  // write bf16 H (channel layout: h*64 + c)
#pragma unroll
  for (int i = 0; i < 4; i++) {
    int r = r0 + ty*4 + i;
    if (r < N_NODES) {
      ushort4 p;
      p.x = f2bf(acc[i][0]); p.y = f2bf(acc[i][1]);
      p.z = f2bf(acc[i][2]); p.w = f2bf(acc[i][3]);
      *reinterpret_cast<ushort4*>(&H16[(size_t)r * C + h * HID + tx*4]) = p;
    }
  }
  // fused attention-score epilogue: s = h . a
  float4 as4 = *reinterpret_cast<const float4*>(&a_src[h * HID + tx*4]);
  float4 ad4 = *reinterpret_cast<const float4*>(&a_dst[h * HID + tx*4]);
#pragma unroll
  for (int i = 0; i < 4; i++) {
    Ps[ty*4 + i][tx] = acc[i][0]*as4.x + acc[i][1]*as4.y + acc[i][2]*as4.z + acc[i][3]*as4.w;
    Pd[ty*4 + i][tx] = acc[i][0]*ad4.x + acc[i][1]*ad4.y + acc[i][2]*ad4.z + acc[i][3]*ad4.w;
  }
  __syncthreads();
  if (tid < 64 && r0 + tid < N_NODES) {
    float s = 0.f, d = 0.f;
#pragma unroll
    for (int t = 0; t < 16; t++) { s += Ps[tid][t]; d += Pd[tid][t]; }
    s_src[(r0 + tid) * NHEAD + h] = s;
    s_dst[(r0 + tid) * NHEAD + h] = d;
  }
}

// ---------------- GEMM1: elu(bn(Hprev)) @ W1[h] -> H16 bf16 + s_src/s_dst ----------------
__global__ __launch_bounds__(256) void k_gemm1(const float* __restrict__ Hprev,
                                               const float* __restrict__ W,
                                               const float* __restrict__ scale,
                                               const float* __restrict__ shift,
                                               const float* __restrict__ a_src,
                                               const float* __restrict__ a_dst,
                                               unsigned short* __restrict__ H16,
                                               float* __restrict__ s_src,
                                               float* __restrict__ s_dst){
  __shared__ float As[64][68];
  __shared__ float Bs[64][68];
  __shared__ float Ps[64][16];
  __shared__ float Pd[64][16];
  int r0 = blockIdx.x * 64;
  int h  = blockIdx.y;
  int tid = threadIdx.x;
  int tx = tid & 15, ty = tid >> 4;
#pragma unroll
  for (int i = 0; i < 4; i++) {
    int idx = tid + i * 256;
    int r = idx >> 4, kv = (idx & 15) * 4;
    float4 v = make_float4(0.f, 0.f, 0.f, 0.f);
    if (r0 + r < N_NODES)
      v = *reinterpret_cast<const float4*>(&Hprev[(size_t)(r0 + r) * C + h * HID + kv]);
    float4 sc = *reinterpret_cast<const float4*>(&scale[h * HID + kv]);
    float4 sh = *reinterpret_cast<const float4*>(&shift[h * HID + kv]);
    As[r][kv]   = elu(sc.x * v.x + sh.x);
    As[r][kv+1] = elu(sc.y * v.y + sh.y);
    As[r][kv+2] = elu(sc.z * v.z + sh.z);
    As[r][kv+3] = elu(sc.w * v.w + sh.w);
  }
#pragma unroll
  for (int i = 0; i < 4; i++) {
    int idx = tid + i * 256;
    int k = idx >> 4, cv = (idx & 15) * 4;
    float4 v = *reinterpret_cast<const float4*>(&W[((size_t)h * HID + k) * HID + cv]);
    Bs[k][cv] = v.x; Bs[k][cv+1] = v.y; Bs[k][cv+2] = v.z; Bs[k][cv+3] = v.w;
  }
  __syncthreads();
  float acc[4][4] = {};
#pragma unroll
  for (int k = 0; k < 64; k++) {
    float a[4], b[4];
#pragma unroll
    for (int i = 0; i < 4; i++) a[i] = As[ty*4 + i][k];
#pragma unroll
    for (int j = 0; j < 4; j++) b[j] = Bs[k][tx*4 + j];
#pragma unroll
    for (int i = 0; i < 4; i++)
#pragma unroll
      for (int j = 0; j < 4; j++) acc[i][j] += a[i] * b[j];
  }
#pragma unroll
  for (int i = 0; i < 4; i++) {
    int r = r0 + ty*4 + i;
    if (r < N_NODES) {
      ushort4 p;
      p.x = f2bf(acc[i][0]); p.y = f2bf(acc[i][1]);
      p.z = f2bf(acc[i][2]); p.w = f2bf(acc[i][3]);
      *reinterpret_cast<ushort4*>(&H16[(size_t)r * C + h * HID + tx*4]) = p;
    }
  }
  float4 as4 = *reinterpret_cast<const float4*>(&a_src[h * HID + tx*4]);
  float4 ad4 = *reinterpret_cast<const float4*>(&a_dst[h * HID + tx*4]);
#pragma unroll
  for (int i = 0; i < 4; i++) {
    Ps[ty*4 + i][tx] = acc[i][0]*as4.x + acc[i][1]*as4.y + acc[i][2]*as4.z + acc[i][3]*as4.w;
    Pd[ty*4 + i][tx] = acc[i][0]*ad4.x + acc[i][1]*ad4.y + acc[i][2]*ad4.z + acc[i][3]*ad4.w;
  }
  __syncthreads();
  if (tid < 64 && r0 + tid < N_NODES) {
    float s = 0.f, d = 0.f;
#pragma unroll
    for (int t = 0; t < 16; t++) { s += Ps[tid][t]; d += Pd[tid][t]; }
    s_src[(r0 + tid) * NHEAD + h] = s;
    s_dst[(r0 + tid) * NHEAD + h] = d;
  }
}

// ---------------- single-pass softmax + aggregation (1 wave / node, bf16 gather) ----------------
// softmax is shift-invariant; logits are O(+-8) here so exp() cannot overflow -> skip segment max.
__global__ __launch_bounds__(256) void k_aggregate(const unsigned short* __restrict__ H16,
                                                   const float* __restrict__ s_src,
                                                   const float* __restrict__ s_dst,
                                                   const int* __restrict__ off,
                                                   const int* __restrict__ csr,
                                                   const float* __restrict__ bias,
                                                   float* __restrict__ Hout){
  __shared__ float alds[4][64][8];
  int wv = threadIdx.x >> 6, lane = threadIdx.x & 63;
  int n = blockIdx.x * 4 + wv;
  if (n >= N_NODES) return;
  int e0 = off[n], deg = off[n + 1] - e0;
  int hsel = lane >> 3;   // this lane's 8 channels [lane*8, lane*8+8) all live in head lane>>3

  float sd[NHEAD];
#pragma unroll
  for (int h = 0; h < NHEAD; h++) sd[h] = s_dst[n * NHEAD + h];

  float acc[8] = {};
  float dnl[NHEAD] = {};

  for (int base = 0; base < deg; base += 64) {
    int e = base + lane;
    int cnt = min(64, deg - base);
    int s_reg = 0;
    if (e < deg) {
      s_reg = csr[e0 + e];
      const float4* sp = reinterpret_cast<const float4*>(&s_src[s_reg * NHEAD]);
      float4 s01 = sp[0], s23 = sp[1];
      float sv[8] = { s01.x, s01.y, s01.z, s01.w, s23.x, s23.y, s23.z, s23.w };
#pragma unroll
      for (int h = 0; h < NHEAD; h++) {
        float ex = __expf(lrelu(sv[h] + sd[h]));
        dnl[h] += ex;
        alds[wv][lane][h] = ex;
      }
    }
    // wave-local LDS write->read; compiler inserts the lgkmcnt wait
#pragma unroll 2
    for (int j = 0; j < cnt; j++) {
      int s = __shfl(s_reg, j, 64);
      float a = alds[wv][j][hsel];
      const uint4* rp = reinterpret_cast<const uint4*>(H16 + (size_t)s * C);
      uint4 v = rp[lane];
      acc[0] += a * bflo(v.x); acc[1] += a * bfhi(v.x);
      acc[2] += a * bflo(v.y); acc[3] += a * bfhi(v.y);
      acc[4] += a * bflo(v.z); acc[5] += a * bfhi(v.z);
      acc[6] += a * bflo(v.w); acc[7] += a * bfhi(v.w);
    }
  }

  // reduce denominators across the wave, select this lane's head
  float mydn = 0.f;
#pragma unroll
  for (int h = 0; h < NHEAD; h++) {
    float d = dnl[h];
#pragma unroll
    for (int o = 32; o; o >>= 1) d += __shfl_xor(d, o, 64);
    if (hsel == h) mydn = d;
  }
  float inv = 1.f / (mydn + SM_EPS);

  float* op = Hout + (size_t)n * C + lane * 8;
  const float* bp = bias + lane * 8;
  float4 o0, o1;
  o0.x = acc[0]*inv + bp[0]; o0.y = acc[1]*inv + bp[1];
  o0.z = acc[2]*inv + bp[2]; o0.w = acc[3]*inv + bp[3];
  o1.x = acc[4]*inv + bp[4]; o1.y = acc[5]*inv + bp[5];
  o1.z = acc[6]*inv + bp[6]; o1.w = acc[7]*inv + bp[7];
  reinterpret_cast<float4*>(op)[0] = o0;
  reinterpret_cast<float4*>(op)[1] = o1;
}

// ---------------- BatchNorm stats ----------------
__global__ void k_zero_stats(float* stats){ stats[threadIdx.x] = 0.f; }  // 1024 threads
__global__ __launch_bounds__(256) void k_bn_stats(const float* __restrict__ Hm, float* __restrict__ stats){
  int c = threadIdx.x;
  float s0 = 0.f, q0 = 0.f, s1 = 0.f, q1 = 0.f;
  for (int r = blockIdx.x; r < N_NODES; r += gridDim.x) {
    float v0 = Hm[(size_t)r * C + c];
    float v1 = Hm[(size_t)r * C + c + 256];
    s0 += v0; q0 += v0 * v0; s1 += v1; q1 += v1 * v1;
  }
  atomicAdd(&stats[c], s0);
  atomicAdd(&stats[c + 256], s1);
  atomicAdd(&stats[C + c], q0);
  atomicAdd(&stats[C + c + 256], q1);
}
__global__ void k_bn_finalize(const float* __restrict__ stats, const float* __restrict__ gamma,
                              const float* __restrict__ beta, float* __restrict__ scale,
                              float* __restrict__ shift){
  int c = threadIdx.x;  // 512 threads
  float mean = stats[c] * (1.f / N_NODES);
  float var  = stats[C + c] * (1.f / N_NODES) - mean * mean;
  float sc = gamma[c] * rsqrtf(var + BN_EPS);
  scale[c] = sc;
  shift[c] = beta[c] - mean * sc;
}

// ---------------- final: out = elu(bn(H)) @ Wc + bc ----------------
__global__ __launch_bounds__(256) void k_final(const float* __restrict__ Hm,
                                               const float* __restrict__ scale,
                                               const float* __restrict__ shift,
                                               const float* __restrict__ Wc,
                                               const float* __restrict__ bc,
                                               float* __restrict__ out){
  int wave = threadIdx.x >> 6, lane = threadIdx.x & 63;
  int n = blockIdx.x * 4 + wave;
  if (n >= N_NODES) return;
  float a0 = 0.f, a1 = 0.f;
#pragma unroll
  for (int h = 0; h < NHEAD; h++) {
    int ch = h * HID + lane;
    float v = Hm[(size_t)n * C + ch];
    v = scale[ch] * v + shift[ch];
    v = elu(v);
    a0 += v * Wc[ch * 2 + 0];
    a1 += v * Wc[ch * 2 + 1];
  }
#pragma unroll
  for (int o = 32; o; o >>= 1) { a0 += __shfl_xor(a0, o, 64); a1 += __shfl_xor(a1, o, 64); }
  if (lane == 0) { out[n * 2 + 0] = a0 + bc[0]; out[n * 2 + 1] = a1 + bc[1]; }
}

extern "C" void kernel_launch(void* const* d_in, const int* in_sizes, int n_in,
                              void* d_out, int out_size, void* d_ws, size_t ws_size,
                              hipStream_t stream) {
  const float* x      = (const float*)d_in[0];
  const int*   ei     = (const int*)d_in[1];
  const float* W0     = (const float*)d_in[2];
  const float* a_src0 = (const float*)d_in[3];
  const float* a_dst0 = (const float*)d_in[4];
  const float* b0     = (const float*)d_in[5];
  const float* gamma0 = (const float*)d_in[6];
  const float* beta0  = (const float*)d_in[7];
  const float* W1     = (const float*)d_in[8];
  const float* a_src1 = (const float*)d_in[9];
  const float* a_dst1 = (const float*)d_in[10];
  const float* b1     = (const float*)d_in[11];
  const float* gamma1 = (const float*)d_in[12];
  const float* beta1  = (const float*)d_in[13];
  const float* Wc     = (const float*)d_in[14];
  const float* bc     = (const float*)d_in[15];
  float* out = (float*)d_out;

  char* ws = (char*)d_ws;
  size_t o = 0;
  auto alloc = [&](size_t bytes) { char* p = ws + o; o = (o + bytes + 255) & ~(size_t)255; return p; };
  int*   flag    = (int*)  alloc(4);
  int*   src32   = (int*)  alloc((size_t)N_EDGES * 4);
  int*   dst32   = (int*)  alloc((size_t)N_EDGES * 4);
  int*   counts  = (int*)  alloc((size_t)N_NODES * 4);
  int*   excl    = (int*)  alloc((size_t)N_NODES * 4);
  int*   bsum    = (int*)  alloc(256 * 4);
  int*   off     = (int*)  alloc((size_t)(N_NODES + 1) * 4);
  int*   cursor  = (int*)  alloc((size_t)N_NODES * 4);
  int*   csr     = (int*)  alloc((size_t)E_TOT * 4);
  float* s_src   = (float*)alloc((size_t)N_NODES * NHEAD * 4);
  float* s_dst   = (float*)alloc((size_t)N_NODES * NHEAD * 4);
  float* stats   = (float*)alloc(1024 * 4);
  float* scale   = (float*)alloc(C * 4);
  float* shift   = (float*)alloc(C * 4);
  unsigned short* h16 = (unsigned short*)alloc((size_t)N_NODES * C * 2);
  float* h_f     = (float*)alloc((size_t)N_NODES * C * 4);

  const int GE = (N_EDGES + 255) / 256;      // 3125
  const int GN = (N_NODES + 255) / 256;      // 196
  const int GW = (N_NODES + 3) / 4;          // 12500
  const int GR = (N_NODES + 63) / 64;        // 782

  // edges -> int32 + degree counts, CSR by dst (with self loops)
  k_detect<<<1, 64, 0, stream>>>(ei, flag);
  k_init_counts<<<GN, 256, 0, stream>>>(counts);
  k_extract_count<<<GE, 256, 0, stream>>>(ei, flag, src32, dst32, counts);
  k_scan1<<<GN, 256, 0, stream>>>(counts, excl, bsum);
  k_scan2<<<1, 256, 0, stream>>>(bsum);
  k_scan3<<<GN, 256, 0, stream>>>(excl, bsum, off, cursor);
  k_scatter_self<<<GN, 256, 0, stream>>>(cursor, csr);
  k_scatter_edges<<<GE, 256, 0, stream>>>(src32, dst32, cursor, csr);

  // ----- layer 0 -----
  k_gemm0<<<dim3(GR, NHEAD), 256, 0, stream>>>(x, W0, a_src0, a_dst0, h16, s_src, s_dst);
  k_aggregate<<<GW, 256, 0, stream>>>(h16, s_src, s_dst, off, csr, b0, h_f);
  k_zero_stats<<<1, 1024, 0, stream>>>(stats);
  k_bn_stats<<<256, 256, 0, stream>>>(h_f, stats);
  k_bn_finalize<<<1, 512, 0, stream>>>(stats, gamma0, beta0, scale, shift);

  // ----- layer 1 (BN0+ELU fused into GEMM1 load) -----
  k_gemm1<<<dim3(GR, NHEAD), 256, 0, stream>>>(h_f, W1, scale, shift, a_src1, a_dst1, h16, s_src, s_dst);
  k_aggregate<<<GW, 256, 0, stream>>>(h16, s_src, s_dst, off, csr, b1, h_f);
  k_zero_stats<<<1, 1024, 0, stream>>>(stats);
  k_bn_stats<<<256, 256, 0, stream>>>(h_f, stats);
  k_bn_finalize<<<1, 512, 0, stream>>>(stats, gamma1, beta1, scale, shift);

  // ----- classifier (BN1+ELU fused) -----
  k_final<<<GW, 256, 0, stream>>>(h_f, scale, shift, Wc, bc, out);
}

// Round 3
// 600.856 us; speedup vs baseline: 2.0895x; 1.3799x over previous
//
#include <hip/hip_runtime.h>
#include <hip/hip_bf16.h>
#include <math.h>
#include <stdint.h>

#define N_NODES 50000
#define N_EDGES 800000
#define E_TOT   (N_EDGES + N_NODES)   // 850000 with self loops
#define IN_CH   128
#define HID     64
#define NHEAD   8
#define C       512                   // NHEAD*HID
#define NEG_SLOPE 0.2f
#define BN_EPS    1e-5f
#define SM_EPS    1e-16f
#define SCAN_B    196                 // ceil(N_NODES/256)

typedef __attribute__((ext_vector_type(8))) short bf16x8;
typedef __attribute__((ext_vector_type(4))) float f32x4;

__device__ __forceinline__ float lrelu(float x){ return x > 0.f ? x : NEG_SLOPE * x; }
__device__ __forceinline__ float elu(float x){ return x > 0.f ? x : __expf(x) - 1.f; }
__device__ __forceinline__ float bflo(unsigned u){ return __uint_as_float(u << 16); }
__device__ __forceinline__ float bfhi(unsigned u){ return __uint_as_float(u & 0xffff0000u); }
__device__ __forceinline__ unsigned short f2bf(float f){
  unsigned u = __float_as_uint(f);
  unsigned r = u + 0x7fffu + ((u >> 16) & 1u);   // RNE
  return (unsigned short)(r >> 16);
}

// ---------------- edge dtype probe + extraction (+count fused) ----------------
__global__ void k_detect(const int* __restrict__ ei, int* flag){
  if (threadIdx.x == 0 && blockIdx.x == 0) {
    int f = 1;
    for (int i = 0; i < 32; i++) if (ei[2*i + 1] != 0) f = 0;  // int64 => high words 0
    *flag = f;
  }
}
__global__ void k_init_counts(int* counts){
  int i = blockIdx.x * 256 + threadIdx.x;
  if (i < N_NODES) counts[i] = 1;            // self loop
}
__global__ void k_extract_count(const int* __restrict__ ei, const int* __restrict__ flag,
                                int* __restrict__ src32, int* __restrict__ dst32,
                                int* counts){
  int e = blockIdx.x * 256 + threadIdx.x;
  if (e >= N_EDGES) return;
  int s, d;
  if (*flag) {
    const long long* e64 = (const long long*)ei;
    s = (int)e64[e];
    d = (int)e64[(size_t)N_EDGES + e];
  } else {
    s = ei[e];
    d = ei[N_EDGES + e];
  }
  src32[e] = s; dst32[e] = d;
  atomicAdd(&counts[d], 1);
}

// ---------------- multi-block exclusive scan ----------------
__global__ void k_scan1(const int* __restrict__ counts, int* __restrict__ excl, int* __restrict__ bsum){
  __shared__ int s[256];
  int tid = threadIdx.x;
  int i = blockIdx.x * 256 + tid;
  int v = (i < N_NODES) ? counts[i] : 0;
  s[tid] = v; __syncthreads();
#pragma unroll
  for (int d = 1; d < 256; d <<= 1) {
    int t = (tid >= d) ? s[tid - d] : 0;
    __syncthreads(); s[tid] += t; __syncthreads();
  }
  if (i < N_NODES) excl[i] = s[tid] - v;
  if (tid == 255) bsum[blockIdx.x] = s[255];
}
__global__ void k_scan2(int* bsum){
  __shared__ int s[256];
  int tid = threadIdx.x;
  int v = (tid < SCAN_B) ? bsum[tid] : 0;
  s[tid] = v; __syncthreads();
#pragma unroll
  for (int d = 1; d < 256; d <<= 1) {
    int t = (tid >= d) ? s[tid - d] : 0;
    __syncthreads(); s[tid] += t; __syncthreads();
  }
  if (tid < SCAN_B) bsum[tid] = s[tid] - v;
}
__global__ void k_scan3(const int* __restrict__ excl, const int* __restrict__ bsum,
                        int* __restrict__ off, int* __restrict__ cursor){
  int i = blockIdx.x * 256 + threadIdx.x;
  if (i < N_NODES) { int o = excl[i] + bsum[blockIdx.x]; off[i] = o; cursor[i] = o; }
  if (i == 0) off[N_NODES] = E_TOT;
}
__global__ void k_scatter_self(int* cursor, int* __restrict__ csr_src){
  int i = blockIdx.x * 256 + threadIdx.x;
  if (i < N_NODES) { int p = atomicAdd(&cursor[i], 1); csr_src[p] = i; }
}
__global__ void k_scatter_edges(const int* __restrict__ src, const int* __restrict__ dst,
                                int* cursor, int* __restrict__ csr_src){
  int e = blockIdx.x * 256 + threadIdx.x;
  if (e < N_EDGES) { int d = dst[e]; int p = atomicAdd(&cursor[d], 1); csr_src[p] = src[e]; }
}

// ---------------- precision prep: X -> bf16, W -> bf16 transposed [h][c][k] ----------------
__global__ void k_cast_x(const float* __restrict__ X, unsigned short* __restrict__ X16){
  size_t i = (size_t)(blockIdx.x * 256 + threadIdx.x) * 4;   // 6.4M elems, exact
  float4 v = *reinterpret_cast<const float4*>(&X[i]);
  ushort4 p; p.x = f2bf(v.x); p.y = f2bf(v.y); p.z = f2bf(v.z); p.w = f2bf(v.w);
  *reinterpret_cast<ushort4*>(&X16[i]) = p;
}
// W[h][K][64] -> Bt[h][64][K]
template<int K>
__global__ void k_transpose_w(const float* __restrict__ W, unsigned short* __restrict__ Bt){
  int i = blockIdx.x * 256 + threadIdx.x;     // out index, grid covers 8*64*K
  int k = i % K; int rem = i / K; int c = rem & 63; int h = rem >> 6;
  Bt[i] = f2bf(W[((size_t)h * K + k) * 64 + c]);
}

// ---------------- MFMA GEMM0: X16[N,128] @ W0 -> H16 bf16 + s scores ----------------
__global__ __launch_bounds__(256) void k_gemm0(const unsigned short* __restrict__ X16,
                                               const unsigned short* __restrict__ Bt,   // [h][64][128]
                                               const float* __restrict__ a_src,
                                               const float* __restrict__ a_dst,
                                               unsigned short* __restrict__ H16,
                                               float* __restrict__ s_src,
                                               float* __restrict__ s_dst){
  __shared__ unsigned short LA[64 * 136];   // [row][k], row stride 272B (2-way banks, 16B aligned)
  __shared__ unsigned short LB[64 * 136];   // [col][k]
  int r0 = blockIdx.x * 64, h = blockIdx.y;
  int tid = threadIdx.x;
#pragma unroll
  for (int i = 0; i < 4; i++) {
    int idx = tid + i * 256;
    int r = idx >> 4, l16 = idx & 15;
    uint4 v = make_uint4(0, 0, 0, 0);
    if (r0 + r < N_NODES)
      v = *reinterpret_cast<const uint4*>(&X16[(size_t)(r0 + r) * IN_CH + l16 * 8]);
    *reinterpret_cast<uint4*>(&LA[r * 136 + l16 * 8]) = v;
  }
#pragma unroll
  for (int i = 0; i < 4; i++) {
    int idx = tid + i * 256;
    int c = idx >> 4, l16 = idx & 15;
    uint4 v = *reinterpret_cast<const uint4*>(&Bt[(size_t)h * 8192 + c * 128 + l16 * 8]);
    *reinterpret_cast<uint4*>(&LB[c * 136 + l16 * 8]) = v;
  }
  __syncthreads();
  int w = tid >> 6, l = tid & 63;
  int lr = l & 15, lg = l >> 4;
  f32x4 acc[4] = {};
#pragma unroll
  for (int kf = 0; kf < 4; kf++) {
    bf16x8 af = *reinterpret_cast<const bf16x8*>(&LA[(w * 16 + lr) * 136 + kf * 32 + lg * 8]);
#pragma unroll
    for (int cf = 0; cf < 4; cf++) {
      bf16x8 bfr = *reinterpret_cast<const bf16x8*>(&LB[(cf * 16 + lr) * 136 + kf * 32 + lg * 8]);
      acc[cf] = __builtin_amdgcn_mfma_f32_16x16x32_bf16(af, bfr, acc[cf], 0, 0, 0);
    }
  }
  // H16 write: D layout col=lane&15, row=(lane>>4)*4+reg
#pragma unroll
  for (int cf = 0; cf < 4; cf++)
#pragma unroll
    for (int rr = 0; rr < 4; rr++) {
      int gr = r0 + w * 16 + lg * 4 + rr;
      if (gr < N_NODES)
        H16[(size_t)gr * C + h * HID + cf * 16 + lr] = f2bf(acc[cf][rr]);
    }
  // fused s = h.a epilogue
  float ps[4] = {}, pd[4] = {};
#pragma unroll
  for (int cf = 0; cf < 4; cf++) {
    float as_ = a_src[h * HID + cf * 16 + lr];
    float ad_ = a_dst[h * HID + cf * 16 + lr];
#pragma unroll
    for (int rr = 0; rr < 4; rr++) { ps[rr] += acc[cf][rr] * as_; pd[rr] += acc[cf][rr] * ad_; }
  }
#pragma unroll
  for (int rr = 0; rr < 4; rr++)
#pragma unroll
    for (int o = 1; o < 16; o <<= 1) { ps[rr] += __shfl_xor(ps[rr], o, 64); pd[rr] += __shfl_xor(pd[rr], o, 64); }
  if (lr == 0) {
#pragma unroll
    for (int rr = 0; rr < 4; rr++) {
      int gr = r0 + w * 16 + lg * 4 + rr;
      if (gr < N_NODES) { s_src[gr * NHEAD + h] = ps[rr]; s_dst[gr * NHEAD + h] = pd[rr]; }
    }
  }
}

// ---------------- MFMA GEMM1: elu(bn(Hprev)) @ W1 -> H16 bf16 + s scores ----------------
__global__ __launch_bounds__(256) void k_gemm1(const float* __restrict__ Hprev,
                                               const unsigned short* __restrict__ Bt,   // [h][64][64]
                                               const float* __restrict__ scale,
                                               const float* __restrict__ shift,
                                               const float* __restrict__ a_src,
                                               const float* __restrict__ a_dst,
                                               unsigned short* __restrict__ H16,
                                               float* __restrict__ s_src,
                                               float* __restrict__ s_dst){
  __shared__ unsigned short LA[64 * 72];    // [row][k], row stride 144B
  __shared__ unsigned short LB[64 * 72];
  int r0 = blockIdx.x * 64, h = blockIdx.y;
  int tid = threadIdx.x;
#pragma unroll
  for (int i = 0; i < 4; i++) {
    int idx = tid + i * 256;
    int r = idx >> 4, l16 = idx & 15;
    float4 v = make_float4(0.f, 0.f, 0.f, 0.f);
    if (r0 + r < N_NODES)
      v = *reinterpret_cast<const float4*>(&Hprev[(size_t)(r0 + r) * C + h * HID + l16 * 4]);
    float4 sc = *reinterpret_cast<const float4*>(&scale[h * HID + l16 * 4]);
    float4 sh = *reinterpret_cast<const float4*>(&shift[h * HID + l16 * 4]);
    ushort4 p;
    p.x = f2bf(elu(sc.x * v.x + sh.x));
    p.y = f2bf(elu(sc.y * v.y + sh.y));
    p.z = f2bf(elu(sc.z * v.z + sh.z));
    p.w = f2bf(elu(sc.w * v.w + sh.w));
    *reinterpret_cast<ushort4*>(&LA[r * 72 + l16 * 4]) = p;
  }
#pragma unroll
  for (int i = 0; i < 2; i++) {
    int idx = tid + i * 256;
    int c = idx >> 3, l8 = idx & 7;
    uint4 v = *reinterpret_cast<const uint4*>(&Bt[(size_t)h * 4096 + c * 64 + l8 * 8]);
    *reinterpret_cast<uint4*>(&LB[c * 72 + l8 * 8]) = v;
  }
  __syncthreads();
  int w = tid >> 6, l = tid & 63;
  int lr = l & 15, lg = l >> 4;
  f32x4 acc[4] = {};
#pragma unroll
  for (int kf = 0; kf < 2; kf++) {
    bf16x8 af = *reinterpret_cast<const bf16x8*>(&LA[(w * 16 + lr) * 72 + kf * 32 + lg * 8]);
#pragma unroll
    for (int cf = 0; cf < 4; cf++) {
      bf16x8 bfr = *reinterpret_cast<const bf16x8*>(&LB[(cf * 16 + lr) * 72 + kf * 32 + lg * 8]);
      acc[cf] = __builtin_amdgcn_mfma_f32_16x16x32_bf16(af, bfr, acc[cf], 0, 0, 0);
    }
  }
#pragma unroll
  for (int cf = 0; cf < 4; cf++)
#pragma unroll
    for (int rr = 0; rr < 4; rr++) {
      int gr = r0 + w * 16 + lg * 4 + rr;
      if (gr < N_NODES)
        H16[(size_t)gr * C + h * HID + cf * 16 + lr] = f2bf(acc[cf][rr]);
    }
  float ps[4] = {}, pd[4] = {};
#pragma unroll
  for (int cf = 0; cf < 4; cf++) {
    float as_ = a_src[h * HID + cf * 16 + lr];
    float ad_ = a_dst[h * HID + cf * 16 + lr];
#pragma unroll
    for (int rr = 0; rr < 4; rr++) { ps[rr] += acc[cf][rr] * as_; pd[rr] += acc[cf][rr] * ad_; }
  }
#pragma unroll
  for (int rr = 0; rr < 4; rr++)
#pragma unroll
    for (int o = 1; o < 16; o <<= 1) { ps[rr] += __shfl_xor(ps[rr], o, 64); pd[rr] += __shfl_xor(pd[rr], o, 64); }
  if (lr == 0) {
#pragma unroll
    for (int rr = 0; rr < 4; rr++) {
      int gr = r0 + w * 16 + lg * 4 + rr;
      if (gr < N_NODES) { s_src[gr * NHEAD + h] = ps[rr]; s_dst[gr * NHEAD + h] = pd[rr]; }
    }
  }
}

// ---------------- single-pass softmax + aggregation (1 wave / node, bf16 gather) ----------------
__global__ __launch_bounds__(256) void k_aggregate(const unsigned short* __restrict__ H16,
                                                   const float* __restrict__ s_src,
                                                   const float* __restrict__ s_dst,
                                                   const int* __restrict__ off,
                                                   const int* __restrict__ csr,
                                                   const float* __restrict__ bias,
                                                   float* __restrict__ Hout){
  __shared__ float alds[4][64][8];
  int wv = threadIdx.x >> 6, lane = threadIdx.x & 63;
  int n = blockIdx.x * 4 + wv;
  if (n >= N_NODES) return;
  int e0 = off[n], deg = off[n + 1] - e0;
  int hsel = lane >> 3;

  float sd[NHEAD];
#pragma unroll
  for (int h = 0; h < NHEAD; h++) sd[h] = s_dst[n * NHEAD + h];

  float acc[8] = {};
  float dnl[NHEAD] = {};

  for (int base = 0; base < deg; base += 64) {
    int e = base + lane;
    int cnt = min(64, deg - base);
    int s_reg = 0;
    if (e < deg) {
      s_reg = csr[e0 + e];
      const float4* sp = reinterpret_cast<const float4*>(&s_src[s_reg * NHEAD]);
      float4 s01 = sp[0], s23 = sp[1];
      float sv[8] = { s01.x, s01.y, s01.z, s01.w, s23.x, s23.y, s23.z, s23.w };
#pragma unroll
      for (int h = 0; h < NHEAD; h++) {
        float ex = __expf(lrelu(sv[h] + sd[h]));
        dnl[h] += ex;
        alds[wv][lane][h] = ex;
      }
    }
#pragma unroll 2
    for (int j = 0; j < cnt; j++) {
      int s = __shfl(s_reg, j, 64);
      float a = alds[wv][j][hsel];
      const uint4* rp = reinterpret_cast<const uint4*>(H16 + (size_t)s * C);
      uint4 v = rp[lane];
      acc[0] += a * bflo(v.x); acc[1] += a * bfhi(v.x);
      acc[2] += a * bflo(v.y); acc[3] += a * bfhi(v.y);
      acc[4] += a * bflo(v.z); acc[5] += a * bfhi(v.z);
      acc[6] += a * bflo(v.w); acc[7] += a * bfhi(v.w);
    }
  }

  float mydn = 0.f;
#pragma unroll
  for (int h = 0; h < NHEAD; h++) {
    float d = dnl[h];
#pragma unroll
    for (int o = 32; o; o >>= 1) d += __shfl_xor(d, o, 64);
    if (hsel == h) mydn = d;
  }
  float inv = 1.f / (mydn + SM_EPS);

  float* op = Hout + (size_t)n * C + lane * 8;
  const float* bp = bias + lane * 8;
  float4 o0, o1;
  o0.x = acc[0]*inv + bp[0]; o0.y = acc[1]*inv + bp[1];
  o0.z = acc[2]*inv + bp[2]; o0.w = acc[3]*inv + bp[3];
  o1.x = acc[4]*inv + bp[4]; o1.y = acc[5]*inv + bp[5];
  o1.z = acc[6]*inv + bp[6]; o1.w = acc[7]*inv + bp[7];
  reinterpret_cast<float4*>(op)[0] = o0;
  reinterpret_cast<float4*>(op)[1] = o1;
}

// ---------------- BatchNorm stats ----------------
__global__ void k_zero_stats(float* stats){ stats[threadIdx.x] = 0.f; }  // 1024 threads
__global__ __launch_bounds__(256) void k_bn_stats(const float* __restrict__ Hm, float* __restrict__ stats){
  int c = threadIdx.x;
  float s0 = 0.f, q0 = 0.f, s1 = 0.f, q1 = 0.f;
  for (int r = blockIdx.x; r < N_NODES; r += gridDim.x) {
    float v0 = Hm[(size_t)r * C + c];
    float v1 = Hm[(size_t)r * C + c + 256];
    s0 += v0; q0 += v0 * v0; s1 += v1; q1 += v1 * v1;
  }
  atomicAdd(&stats[c], s0);
  atomicAdd(&stats[c + 256], s1);
  atomicAdd(&stats[C + c], q0);
  atomicAdd(&stats[C + c + 256], q1);
}
__global__ void k_bn_finalize(const float* __restrict__ stats, const float* __restrict__ gamma,
                              const float* __restrict__ beta, float* __restrict__ scale,
                              float* __restrict__ shift){
  int c = threadIdx.x;  // 512 threads
  float mean = stats[c] * (1.f / N_NODES);
  float var  = stats[C + c] * (1.f / N_NODES) - mean * mean;
  float sc = gamma[c] * rsqrtf(var + BN_EPS);
  scale[c] = sc;
  shift[c] = beta[c] - mean * sc;
}

// ---------------- final: out = elu(bn(H)) @ Wc + bc ----------------
__global__ __launch_bounds__(256) void k_final(const float* __restrict__ Hm,
                                               const float* __restrict__ scale,
                                               const float* __restrict__ shift,
                                               const float* __restrict__ Wc,
                                               const float* __restrict__ bc,
                                               float* __restrict__ out){
  int wave = threadIdx.x >> 6, lane = threadIdx.x & 63;
  int n = blockIdx.x * 4 + wave;
  if (n >= N_NODES) return;
  float a0 = 0.f, a1 = 0.f;
#pragma unroll
  for (int h = 0; h < NHEAD; h++) {
    int ch = h * HID + lane;
    float v = Hm[(size_t)n * C + ch];
    v = scale[ch] * v + shift[ch];
    v = elu(v);
    a0 += v * Wc[ch * 2 + 0];
    a1 += v * Wc[ch * 2 + 1];
  }
#pragma unroll
  for (int o = 32; o; o >>= 1) { a0 += __shfl_xor(a0, o, 64); a1 += __shfl_xor(a1, o, 64); }
  if (lane == 0) { out[n * 2 + 0] = a0 + bc[0]; out[n * 2 + 1] = a1 + bc[1]; }
}

extern "C" void kernel_launch(void* const* d_in, const int* in_sizes, int n_in,
                              void* d_out, int out_size, void* d_ws, size_t ws_size,
                              hipStream_t stream) {
  const float* x      = (const float*)d_in[0];
  const int*   ei     = (const int*)d_in[1];
  const float* W0     = (const float*)d_in[2];
  const float* a_src0 = (const float*)d_in[3];
  const float* a_dst0 = (const float*)d_in[4];
  const float* b0     = (const float*)d_in[5];
  const float* gamma0 = (const float*)d_in[6];
  const float* beta0  = (const float*)d_in[7];
  const float* W1     = (const float*)d_in[8];
  const float* a_src1 = (const float*)d_in[9];
  const float* a_dst1 = (const float*)d_in[10];
  const float* b1     = (const float*)d_in[11];
  const float* gamma1 = (const float*)d_in[12];
  const float* beta1  = (const float*)d_in[13];
  const float* Wc     = (const float*)d_in[14];
  const float* bc     = (const float*)d_in[15];
  float* out = (float*)d_out;

  char* ws = (char*)d_ws;
  size_t o = 0;
  auto alloc = [&](size_t bytes) { char* p = ws + o; o = (o + bytes + 255) & ~(size_t)255; return p; };
  int*   flag    = (int*)  alloc(4);
  int*   src32   = (int*)  alloc((size_t)N_EDGES * 4);
  int*   dst32   = (int*)  alloc((size_t)N_EDGES * 4);
  int*   counts  = (int*)  alloc((size_t)N_NODES * 4);
  int*   excl    = (int*)  alloc((size_t)N_NODES * 4);
  int*   bsum    = (int*)  alloc(256 * 4);
  int*   off     = (int*)  alloc((size_t)(N_NODES + 1) * 4);
  int*   cursor  = (int*)  alloc((size_t)N_NODES * 4);
  int*   csr     = (int*)  alloc((size_t)E_TOT * 4);
  float* s_src   = (float*)alloc((size_t)N_NODES * NHEAD * 4);
  float* s_dst   = (float*)alloc((size_t)N_NODES * NHEAD * 4);
  float* stats   = (float*)alloc(1024 * 4);
  float* scale   = (float*)alloc(C * 4);
  float* shift   = (float*)alloc(C * 4);
  unsigned short* x16  = (unsigned short*)alloc((size_t)N_NODES * IN_CH * 2);
  unsigned short* bt0  = (unsigned short*)alloc((size_t)NHEAD * HID * IN_CH * 2);
  unsigned short* bt1  = (unsigned short*)alloc((size_t)NHEAD * HID * HID * 2);
  unsigned short* h16  = (unsigned short*)alloc((size_t)N_NODES * C * 2);
  float* h_f     = (float*)alloc((size_t)N_NODES * C * 4);

  const int GE = (N_EDGES + 255) / 256;      // 3125
  const int GN = (N_NODES + 255) / 256;      // 196
  const int GW = (N_NODES + 3) / 4;          // 12500
  const int GR = (N_NODES + 63) / 64;        // 782

  // edges -> int32 + degree counts, CSR by dst (with self loops)
  k_detect<<<1, 64, 0, stream>>>(ei, flag);
  k_init_counts<<<GN, 256, 0, stream>>>(counts);
  k_extract_count<<<GE, 256, 0, stream>>>(ei, flag, src32, dst32, counts);

  // precision prep (independent of CSR chain)
  k_cast_x<<<(N_NODES * IN_CH / 4 + 255) / 256, 256, 0, stream>>>(x, x16);
  k_transpose_w<IN_CH><<<(NHEAD * HID * IN_CH + 255) / 256, 256, 0, stream>>>(W0, bt0);
  k_transpose_w<HID><<<(NHEAD * HID * HID + 255) / 256, 256, 0, stream>>>(W1, bt1);

  k_scan1<<<GN, 256, 0, stream>>>(counts, excl, bsum);
  k_scan2<<<1, 256, 0, stream>>>(bsum);
  k_scan3<<<GN, 256, 0, stream>>>(excl, bsum, off, cursor);
  k_scatter_self<<<GN, 256, 0, stream>>>(cursor, csr);
  k_scatter_edges<<<GE, 256, 0, stream>>>(src32, dst32, cursor, csr);

  // ----- layer 0 -----
  k_gemm0<<<dim3(GR, NHEAD), 256, 0, stream>>>(x16, bt0, a_src0, a_dst0, h16, s_src, s_dst);
  k_aggregate<<<GW, 256, 0, stream>>>(h16, s_src, s_dst, off, csr, b0, h_f);
  k_zero_stats<<<1, 1024, 0, stream>>>(stats);
  k_bn_stats<<<256, 256, 0, stream>>>(h_f, stats);
  k_bn_finalize<<<1, 512, 0, stream>>>(stats, gamma0, beta0, scale, shift);

  // ----- layer 1 (BN0+ELU fused into GEMM1 A-staging) -----
  k_gemm1<<<dim3(GR, NHEAD), 256, 0, stream>>>(h_f, bt1, scale, shift, a_src1, a_dst1, h16, s_src, s_dst);
  k_aggregate<<<GW, 256, 0, stream>>>(h16, s_src, s_dst, off, csr, b1, h_f);
  k_zero_stats<<<1, 1024, 0, stream>>>(stats);
  k_bn_stats<<<256, 256, 0, stream>>>(h_f, stats);
  k_bn_finalize<<<1, 512, 0, stream>>>(stats, gamma1, beta1, scale, shift);

  // ----- classifier (BN1+ELU fused) -----
  k_final<<<GW, 256, 0, stream>>>(h_f, scale, shift, Wc, bc, out);
}

// Round 4
// 512.705 us; speedup vs baseline: 2.4488x; 1.1719x over previous
//
#include <hip/hip_runtime.h>
#include <hip/hip_bf16.h>
#include <math.h>
#include <stdint.h>

#define N_NODES 50000
#define N_EDGES 800000
#define E_TOT   (N_EDGES + N_NODES)   // 850000 with self loops
#define IN_CH   128
#define HID     64
#define NHEAD   8
#define C       512                   // NHEAD*HID
#define NEG_SLOPE 0.2f
#define BN_EPS    1e-5f
#define SM_EPS    1e-16f
#define SCAN_B    196                 // ceil(N_NODES/256)
#define STAT_B    256                 // bn_stats blocks

typedef __attribute__((ext_vector_type(8))) short bf16x8;
typedef __attribute__((ext_vector_type(4))) float f32x4;

__device__ __forceinline__ float lrelu(float x){ return x > 0.f ? x : NEG_SLOPE * x; }
__device__ __forceinline__ float elu(float x){ return x > 0.f ? x : __expf(x) - 1.f; }
__device__ __forceinline__ float bflo(unsigned u){ return __uint_as_float(u << 16); }
__device__ __forceinline__ float bfhi(unsigned u){ return __uint_as_float(u & 0xffff0000u); }
__device__ __forceinline__ float bfu(unsigned short u){ return __uint_as_float(((unsigned)u) << 16); }
__device__ __forceinline__ unsigned short f2bf(float f){
  unsigned u = __float_as_uint(f);
  unsigned r = u + 0x7fffu + ((u >> 16) & 1u);   // RNE
  return (unsigned short)(r >> 16);
}

// ---------------- edge dtype probe + extraction (+count fused) ----------------
__global__ void k_detect(const int* __restrict__ ei, int* flag){
  if (threadIdx.x == 0 && blockIdx.x == 0) {
    int f = 1;
    for (int i = 0; i < 32; i++) if (ei[2*i + 1] != 0) f = 0;  // int64 => high words 0
    *flag = f;
  }
}
__global__ void k_init_counts(int* counts){
  int i = blockIdx.x * 256 + threadIdx.x;
  if (i < N_NODES) counts[i] = 1;            // self loop
}
__global__ void k_extract_count(const int* __restrict__ ei, const int* __restrict__ flag,
                                int* __restrict__ src32, int* __restrict__ dst32,
                                int* counts){
  int e = blockIdx.x * 256 + threadIdx.x;
  if (e >= N_EDGES) return;
  int s, d;
  if (*flag) {
    const long long* e64 = (const long long*)ei;
    s = (int)e64[e];
    d = (int)e64[(size_t)N_EDGES + e];
  } else {
    s = ei[e];
    d = ei[N_EDGES + e];
  }
  src32[e] = s; dst32[e] = d;
  atomicAdd(&counts[d], 1);
}

// ---------------- multi-block exclusive scan ----------------
__global__ void k_scan1(const int* __restrict__ counts, int* __restrict__ excl, int* __restrict__ bsum){
  __shared__ int s[256];
  int tid = threadIdx.x;
  int i = blockIdx.x * 256 + tid;
  int v = (i < N_NODES) ? counts[i] : 0;
  s[tid] = v; __syncthreads();
#pragma unroll
  for (int d = 1; d < 256; d <<= 1) {
    int t = (tid >= d) ? s[tid - d] : 0;
    __syncthreads(); s[tid] += t; __syncthreads();
  }
  if (i < N_NODES) excl[i] = s[tid] - v;
  if (tid == 255) bsum[blockIdx.x] = s[255];
}
__global__ void k_scan2(int* bsum){
  __shared__ int s[256];
  int tid = threadIdx.x;
  int v = (tid < SCAN_B) ? bsum[tid] : 0;
  s[tid] = v; __syncthreads();
#pragma unroll
  for (int d = 1; d < 256; d <<= 1) {
    int t = (tid >= d) ? s[tid - d] : 0;
    __syncthreads(); s[tid] += t; __syncthreads();
  }
  if (tid < SCAN_B) bsum[tid] = s[tid] - v;
}
// scan3 also places the self-loop at off[i] and starts cursor past it
__global__ void k_scan3(const int* __restrict__ excl, const int* __restrict__ bsum,
                        int* __restrict__ off, int* __restrict__ cursor, int* __restrict__ csr){
  int i = blockIdx.x * 256 + threadIdx.x;
  if (i < N_NODES) {
    int o = excl[i] + bsum[blockIdx.x];
    off[i] = o; cursor[i] = o + 1; csr[o] = i;
  }
  if (i == 0) off[N_NODES] = E_TOT;
}
__global__ void k_scatter_edges(const int* __restrict__ src, const int* __restrict__ dst,
                                int* cursor, int* __restrict__ csr_src){
  int e = blockIdx.x * 256 + threadIdx.x;
  if (e < N_EDGES) { int d = dst[e]; int p = atomicAdd(&cursor[d], 1); csr_src[p] = src[e]; }
}

// ---------------- precision prep: X -> bf16, W -> bf16 transposed [h][c][k] ----------------
__global__ void k_cast_x(const float* __restrict__ X, unsigned short* __restrict__ X16){
  size_t i = (size_t)(blockIdx.x * 256 + threadIdx.x) * 4;   // 6.4M elems, exact
  float4 v = *reinterpret_cast<const float4*>(&X[i]);
  ushort4 p; p.x = f2bf(v.x); p.y = f2bf(v.y); p.z = f2bf(v.z); p.w = f2bf(v.w);
  *reinterpret_cast<ushort4*>(&X16[i]) = p;
}
// W[h][K][64] -> Bt[h][64][K]
template<int K>
__global__ void k_transpose_w(const float* __restrict__ W, unsigned short* __restrict__ Bt){
  int i = blockIdx.x * 256 + threadIdx.x;     // out index, grid covers 8*64*K
  int k = i % K; int rem = i / K; int c = rem & 63; int h = rem >> 6;
  Bt[i] = f2bf(W[((size_t)h * K + k) * 64 + c]);
}

// ---------------- MFMA GEMM0: X16[N,128] @ W0 -> H16 bf16 + s scores ----------------
__global__ __launch_bounds__(256) void k_gemm0(const unsigned short* __restrict__ X16,
                                               const unsigned short* __restrict__ Bt,   // [h][64][128]
                                               const float* __restrict__ a_src,
                                               const float* __restrict__ a_dst,
                                               unsigned short* __restrict__ H16,
                                               float* __restrict__ s_src,
                                               float* __restrict__ s_dst){
  __shared__ unsigned short LA[64 * 136];   // [row][k], row stride 272B
  __shared__ unsigned short LB[64 * 136];   // [col][k]
  int r0 = blockIdx.x * 64, h = blockIdx.y;
  int tid = threadIdx.x;
#pragma unroll
  for (int i = 0; i < 4; i++) {
    int idx = tid + i * 256;
    int r = idx >> 4, l16 = idx & 15;
    uint4 v = make_uint4(0, 0, 0, 0);
    if (r0 + r < N_NODES)
      v = *reinterpret_cast<const uint4*>(&X16[(size_t)(r0 + r) * IN_CH + l16 * 8]);
    *reinterpret_cast<uint4*>(&LA[r * 136 + l16 * 8]) = v;
  }
#pragma unroll
  for (int i = 0; i < 4; i++) {
    int idx = tid + i * 256;
    int c = idx >> 4, l16 = idx & 15;
    uint4 v = *reinterpret_cast<const uint4*>(&Bt[(size_t)h * 8192 + c * 128 + l16 * 8]);
    *reinterpret_cast<uint4*>(&LB[c * 136 + l16 * 8]) = v;
  }
  __syncthreads();
  int w = tid >> 6, l = tid & 63;
  int lr = l & 15, lg = l >> 4;
  f32x4 acc[4] = {};
#pragma unroll
  for (int kf = 0; kf < 4; kf++) {
    bf16x8 af = *reinterpret_cast<const bf16x8*>(&LA[(w * 16 + lr) * 136 + kf * 32 + lg * 8]);
#pragma unroll
    for (int cf = 0; cf < 4; cf++) {
      bf16x8 bfr = *reinterpret_cast<const bf16x8*>(&LB[(cf * 16 + lr) * 136 + kf * 32 + lg * 8]);
      acc[cf] = __builtin_amdgcn_mfma_f32_16x16x32_bf16(af, bfr, acc[cf], 0, 0, 0);
    }
  }
#pragma unroll
  for (int cf = 0; cf < 4; cf++)
#pragma unroll
    for (int rr = 0; rr < 4; rr++) {
      int gr = r0 + w * 16 + lg * 4 + rr;
      if (gr < N_NODES)
        H16[(size_t)gr * C + h * HID + cf * 16 + lr] = f2bf(acc[cf][rr]);
    }
  float ps[4] = {}, pd[4] = {};
#pragma unroll
  for (int cf = 0; cf < 4; cf++) {
    float as_ = a_src[h * HID + cf * 16 + lr];
    float ad_ = a_dst[h * HID + cf * 16 + lr];
#pragma unroll
    for (int rr = 0; rr < 4; rr++) { ps[rr] += acc[cf][rr] * as_; pd[rr] += acc[cf][rr] * ad_; }
  }
#pragma unroll
  for (int rr = 0; rr < 4; rr++)
#pragma unroll
    for (int o = 1; o < 16; o <<= 1) { ps[rr] += __shfl_xor(ps[rr], o, 64); pd[rr] += __shfl_xor(pd[rr], o, 64); }
  if (lr == 0) {
#pragma unroll
    for (int rr = 0; rr < 4; rr++) {
      int gr = r0 + w * 16 + lg * 4 + rr;
      if (gr < N_NODES) { s_src[gr * NHEAD + h] = ps[rr]; s_dst[gr * NHEAD + h] = pd[rr]; }
    }
  }
}

// ---------------- MFMA GEMM1: elu(bn(Hprev bf16)) @ W1 -> H16 bf16 + s scores ----------------
__global__ __launch_bounds__(256) void k_gemm1(const unsigned short* __restrict__ Hb,
                                               const unsigned short* __restrict__ Bt,   // [h][64][64]
                                               const float* __restrict__ scale,
                                               const float* __restrict__ shift,
                                               const float* __restrict__ a_src,
                                               const float* __restrict__ a_dst,
                                               unsigned short* __restrict__ H16,
                                               float* __restrict__ s_src,
                                               float* __restrict__ s_dst){
  __shared__ unsigned short LA[64 * 72];    // [row][k], row stride 144B
  __shared__ unsigned short LB[64 * 72];
  int r0 = blockIdx.x * 64, h = blockIdx.y;
  int tid = threadIdx.x;
#pragma unroll
  for (int i = 0; i < 4; i++) {
    int idx = tid + i * 256;
    int r = idx >> 4, l16 = idx & 15;
    ushort4 hv = make_ushort4(0, 0, 0, 0);
    if (r0 + r < N_NODES)
      hv = *reinterpret_cast<const ushort4*>(&Hb[(size_t)(r0 + r) * C + h * HID + l16 * 4]);
    float4 sc = *reinterpret_cast<const float4*>(&scale[h * HID + l16 * 4]);
    float4 sh = *reinterpret_cast<const float4*>(&shift[h * HID + l16 * 4]);
    ushort4 p;
    p.x = f2bf(elu(sc.x * bfu(hv.x) + sh.x));
    p.y = f2bf(elu(sc.y * bfu(hv.y) + sh.y));
    p.z = f2bf(elu(sc.z * bfu(hv.z) + sh.z));
    p.w = f2bf(elu(sc.w * bfu(hv.w) + sh.w));
    *reinterpret_cast<ushort4*>(&LA[r * 72 + l16 * 4]) = p;
  }
#pragma unroll
  for (int i = 0; i < 2; i++) {
    int idx = tid + i * 256;
    int c = idx >> 3, l8 = idx & 7;
    uint4 v = *reinterpret_cast<const uint4*>(&Bt[(size_t)h * 4096 + c * 64 + l8 * 8]);
    *reinterpret_cast<uint4*>(&LB[c * 72 + l8 * 8]) = v;
  }
  __syncthreads();
  int w = tid >> 6, l = tid & 63;
  int lr = l & 15, lg = l >> 4;
  f32x4 acc[4] = {};
#pragma unroll
  for (int kf = 0; kf < 2; kf++) {
    bf16x8 af = *reinterpret_cast<const bf16x8*>(&LA[(w * 16 + lr) * 72 + kf * 32 + lg * 8]);
#pragma unroll
    for (int cf = 0; cf < 4; cf++) {
      bf16x8 bfr = *reinterpret_cast<const bf16x8*>(&LB[(cf * 16 + lr) * 72 + kf * 32 + lg * 8]);
      acc[cf] = __builtin_amdgcn_mfma_f32_16x16x32_bf16(af, bfr, acc[cf], 0, 0, 0);
    }
  }
#pragma unroll
  for (int cf = 0; cf < 4; cf++)
#pragma unroll
    for (int rr = 0; rr < 4; rr++) {
      int gr = r0 + w * 16 + lg * 4 + rr;
      if (gr < N_NODES)
        H16[(size_t)gr * C + h * HID + cf * 16 + lr] = f2bf(acc[cf][rr]);
    }
  float ps[4] = {}, pd[4] = {};
#pragma unroll
  for (int cf = 0; cf < 4; cf++) {
    float as_ = a_src[h * HID + cf * 16 + lr];
    float ad_ = a_dst[h * HID + cf * 16 + lr];
#pragma unroll
    for (int rr = 0; rr < 4; rr++) { ps[rr] += acc[cf][rr] * as_; pd[rr] += acc[cf][rr] * ad_; }
  }
#pragma unroll
  for (int rr = 0; rr < 4; rr++)
#pragma unroll
    for (int o = 1; o < 16; o <<= 1) { ps[rr] += __shfl_xor(ps[rr], o, 64); pd[rr] += __shfl_xor(pd[rr], o, 64); }
  if (lr == 0) {
#pragma unroll
    for (int rr = 0; rr < 4; rr++) {
      int gr = r0 + w * 16 + lg * 4 + rr;
      if (gr < N_NODES) { s_src[gr * NHEAD + h] = ps[rr]; s_dst[gr * NHEAD + h] = pd[rr]; }
    }
  }
}

// ---------------- single-pass softmax + aggregation (1 wave / node, bf16 in/out) ----------------
__global__ __launch_bounds__(256) void k_aggregate(const unsigned short* __restrict__ H16,
                                                   const float* __restrict__ s_src,
                                                   const float* __restrict__ s_dst,
                                                   const int* __restrict__ off,
                                                   const int* __restrict__ csr,
                                                   const float* __restrict__ bias,
                                                   unsigned short* __restrict__ HoutB){
  __shared__ float alds[4][64][8];
  int wv = threadIdx.x >> 6, lane = threadIdx.x & 63;
  int n = blockIdx.x * 4 + wv;
  if (n >= N_NODES) return;
  int e0 = off[n], deg = off[n + 1] - e0;
  int hsel = lane >> 3;

  float sd[NHEAD];
#pragma unroll
  for (int h = 0; h < NHEAD; h++) sd[h] = s_dst[n * NHEAD + h];

  float acc[8] = {};
  float dnl[NHEAD] = {};

  for (int base = 0; base < deg; base += 64) {
    int e = base + lane;
    int cnt = min(64, deg - base);
    int s_reg = 0;
    if (e < deg) {
      s_reg = csr[e0 + e];
      const float4* sp = reinterpret_cast<const float4*>(&s_src[s_reg * NHEAD]);
      float4 s01 = sp[0], s23 = sp[1];
      float sv[8] = { s01.x, s01.y, s01.z, s01.w, s23.x, s23.y, s23.z, s23.w };
#pragma unroll
      for (int h = 0; h < NHEAD; h++) {
        float ex = __expf(lrelu(sv[h] + sd[h]));
        dnl[h] += ex;
        alds[wv][lane][h] = ex;
      }
    }
#pragma unroll 2
    for (int j = 0; j < cnt; j++) {
      int s = __shfl(s_reg, j, 64);
      float a = alds[wv][j][hsel];
      const uint4* rp = reinterpret_cast<const uint4*>(H16 + (size_t)s * C);
      uint4 v = rp[lane];
      acc[0] += a * bflo(v.x); acc[1] += a * bfhi(v.x);
      acc[2] += a * bflo(v.y); acc[3] += a * bfhi(v.y);
      acc[4] += a * bflo(v.z); acc[5] += a * bfhi(v.z);
      acc[6] += a * bflo(v.w); acc[7] += a * bfhi(v.w);
    }
  }

  float mydn = 0.f;
#pragma unroll
  for (int h = 0; h < NHEAD; h++) {
    float d = dnl[h];
#pragma unroll
    for (int o = 32; o; o >>= 1) d += __shfl_xor(d, o, 64);
    if (hsel == h) mydn = d;
  }
  float inv = 1.f / (mydn + SM_EPS);

  const float* bp = bias + lane * 8;
  ushort4 p0, p1;
  p0.x = f2bf(acc[0]*inv + bp[0]); p0.y = f2bf(acc[1]*inv + bp[1]);
  p0.z = f2bf(acc[2]*inv + bp[2]); p0.w = f2bf(acc[3]*inv + bp[3]);
  p1.x = f2bf(acc[4]*inv + bp[4]); p1.y = f2bf(acc[5]*inv + bp[5]);
  p1.z = f2bf(acc[6]*inv + bp[6]); p1.w = f2bf(acc[7]*inv + bp[7]);
  unsigned short* op = HoutB + (size_t)n * C + lane * 8;
  *reinterpret_cast<ushort4*>(op) = p0;
  *reinterpret_cast<ushort4*>(op + 4) = p1;
}

// ---------------- BatchNorm stats: per-block partials (no atomics) ----------------
__global__ __launch_bounds__(256) void k_bn_stats(const unsigned short* __restrict__ Hb,
                                                  float* __restrict__ partial){
  __shared__ float red[4][64][16];
  int tid = threadIdx.x, w = tid >> 6, c64 = tid & 63;
  float s[8] = {}, q[8] = {};
  for (int r = blockIdx.x * 4 + w; r < N_NODES; r += gridDim.x * 4) {
    uint4 v = *reinterpret_cast<const uint4*>(&Hb[(size_t)r * C + c64 * 8]);
    float f[8] = { bflo(v.x), bfhi(v.x), bflo(v.y), bfhi(v.y),
                   bflo(v.z), bfhi(v.z), bflo(v.w), bfhi(v.w) };
#pragma unroll
    for (int k = 0; k < 8; k++) { s[k] += f[k]; q[k] += f[k] * f[k]; }
  }
#pragma unroll
  for (int k = 0; k < 8; k++) { red[w][c64][k] = s[k]; red[w][c64][k + 8] = q[k]; }
  __syncthreads();
  if (w == 0) {
#pragma unroll
    for (int k = 0; k < 8; k++) {
      float ss = red[0][c64][k] + red[1][c64][k] + red[2][c64][k] + red[3][c64][k];
      float qq = red[0][c64][k+8] + red[1][c64][k+8] + red[2][c64][k+8] + red[3][c64][k+8];
      partial[(size_t)blockIdx.x * 1024 + c64 * 8 + k] = ss;
      partial[(size_t)blockIdx.x * 1024 + 512 + c64 * 8 + k] = qq;
    }
  }
}
__global__ void k_bn_finalize(const float* __restrict__ partial, const float* __restrict__ gamma,
                              const float* __restrict__ beta, float* __restrict__ scale,
                              float* __restrict__ shift){
  int c = threadIdx.x;  // 512 threads
  float s = 0.f, q = 0.f;
  for (int b = 0; b < STAT_B; b++) {
    s += partial[(size_t)b * 1024 + c];
    q += partial[(size_t)b * 1024 + 512 + c];
  }
  float mean = s * (1.f / N_NODES);
  float var  = q * (1.f / N_NODES) - mean * mean;
  float sc = gamma[c] * rsqrtf(var + BN_EPS);
  scale[c] = sc;
  shift[c] = beta[c] - mean * sc;
}

// ---------------- final: out = elu(bn(Hb)) @ Wc + bc ----------------
__global__ __launch_bounds__(256) void k_final(const unsigned short* __restrict__ Hb,
                                               const float* __restrict__ scale,
                                               const float* __restrict__ shift,
                                               const float* __restrict__ Wc,
                                               const float* __restrict__ bc,
                                               float* __restrict__ out){
  int wave = threadIdx.x >> 6, lane = threadIdx.x & 63;
  int n = blockIdx.x * 4 + wave;
  if (n >= N_NODES) return;
  uint4 v = *reinterpret_cast<const uint4*>(&Hb[(size_t)n * C + lane * 8]);
  float f[8] = { bflo(v.x), bfhi(v.x), bflo(v.y), bfhi(v.y),
                 bflo(v.z), bfhi(v.z), bflo(v.w), bfhi(v.w) };
  float4 sc0 = *reinterpret_cast<const float4*>(&scale[lane * 8]);
  float4 sc1 = *reinterpret_cast<const float4*>(&scale[lane * 8 + 4]);
  float4 sh0 = *reinterpret_cast<const float4*>(&shift[lane * 8]);
  float4 sh1 = *reinterpret_cast<const float4*>(&shift[lane * 8 + 4]);
  float scv[8] = { sc0.x, sc0.y, sc0.z, sc0.w, sc1.x, sc1.y, sc1.z, sc1.w };
  float shv[8] = { sh0.x, sh0.y, sh0.z, sh0.w, sh1.x, sh1.y, sh1.z, sh1.w };
  float a0 = 0.f, a1 = 0.f;
#pragma unroll
  for (int k = 0; k < 8; k++) {
    float t = elu(scv[k] * f[k] + shv[k]);
    int ch = lane * 8 + k;
    a0 += t * Wc[ch * 2 + 0];
    a1 += t * Wc[ch * 2 + 1];
  }
#pragma unroll
  for (int o = 32; o; o >>= 1) { a0 += __shfl_xor(a0, o, 64); a1 += __shfl_xor(a1, o, 64); }
  if (lane == 0) { out[n * 2 + 0] = a0 + bc[0]; out[n * 2 + 1] = a1 + bc[1]; }
}

extern "C" void kernel_launch(void* const* d_in, const int* in_sizes, int n_in,
                              void* d_out, int out_size, void* d_ws, size_t ws_size,
                              hipStream_t stream) {
  const float* x      = (const float*)d_in[0];
  const int*   ei     = (const int*)d_in[1];
  const float* W0     = (const float*)d_in[2];
  const float* a_src0 = (const float*)d_in[3];
  const float* a_dst0 = (const float*)d_in[4];
  const float* b0     = (const float*)d_in[5];
  const float* gamma0 = (const float*)d_in[6];
  const float* beta0  = (const float*)d_in[7];
  const float* W1     = (const float*)d_in[8];
  const float* a_src1 = (const float*)d_in[9];
  const float* a_dst1 = (const float*)d_in[10];
  const float* b1     = (const float*)d_in[11];
  const float* gamma1 = (const float*)d_in[12];
  const float* beta1  = (const float*)d_in[13];
  const float* Wc     = (const float*)d_in[14];
  const float* bc     = (const float*)d_in[15];
  float* out = (float*)d_out;

  char* ws = (char*)d_ws;
  size_t o = 0;
  auto alloc = [&](size_t bytes) { char* p = ws + o; o = (o + bytes + 255) & ~(size_t)255; return p; };
  int*   flag    = (int*)  alloc(4);
  int*   src32   = (int*)  alloc((size_t)N_EDGES * 4);
  int*   dst32   = (int*)  alloc((size_t)N_EDGES * 4);
  int*   counts  = (int*)  alloc((size_t)N_NODES * 4);
  int*   excl    = (int*)  alloc((size_t)N_NODES * 4);
  int*   bsum    = (int*)  alloc(256 * 4);
  int*   off     = (int*)  alloc((size_t)(N_NODES + 1) * 4);
  int*   cursor  = (int*)  alloc((size_t)N_NODES * 4);
  int*   csr     = (int*)  alloc((size_t)E_TOT * 4);
  float* s_src   = (float*)alloc((size_t)N_NODES * NHEAD * 4);
  float* s_dst   = (float*)alloc((size_t)N_NODES * NHEAD * 4);
  float* partial = (float*)alloc((size_t)STAT_B * 1024 * 4);
  float* scale   = (float*)alloc(C * 4);
  float* shift   = (float*)alloc(C * 4);
  unsigned short* x16  = (unsigned short*)alloc((size_t)N_NODES * IN_CH * 2);
  unsigned short* bt0  = (unsigned short*)alloc((size_t)NHEAD * HID * IN_CH * 2);
  unsigned short* bt1  = (unsigned short*)alloc((size_t)NHEAD * HID * HID * 2);
  unsigned short* h16a = (unsigned short*)alloc((size_t)N_NODES * C * 2);
  unsigned short* h16b = (unsigned short*)alloc((size_t)N_NODES * C * 2);

  const int GE = (N_EDGES + 255) / 256;      // 3125
  const int GN = (N_NODES + 255) / 256;      // 196
  const int GW = (N_NODES + 3) / 4;          // 12500
  const int GR = (N_NODES + 63) / 64;        // 782

  // edges -> int32 + degree counts, CSR by dst (with self loops)
  k_detect<<<1, 64, 0, stream>>>(ei, flag);
  k_init_counts<<<GN, 256, 0, stream>>>(counts);
  k_extract_count<<<GE, 256, 0, stream>>>(ei, flag, src32, dst32, counts);

  // precision prep (independent of CSR chain)
  k_cast_x<<<(N_NODES * IN_CH / 4 + 255) / 256, 256, 0, stream>>>(x, x16);
  k_transpose_w<IN_CH><<<(NHEAD * HID * IN_CH + 255) / 256, 256, 0, stream>>>(W0, bt0);
  k_transpose_w<HID><<<(NHEAD * HID * HID + 255) / 256, 256, 0, stream>>>(W1, bt1);

  k_scan1<<<GN, 256, 0, stream>>>(counts, excl, bsum);
  k_scan2<<<1, 256, 0, stream>>>(bsum);
  k_scan3<<<GN, 256, 0, stream>>>(excl, bsum, off, cursor, csr);
  k_scatter_edges<<<GE, 256, 0, stream>>>(src32, dst32, cursor, csr);

  // ----- layer 0 -----
  k_gemm0<<<dim3(GR, NHEAD), 256, 0, stream>>>(x16, bt0, a_src0, a_dst0, h16a, s_src, s_dst);
  k_aggregate<<<GW, 256, 0, stream>>>(h16a, s_src, s_dst, off, csr, b0, h16b);
  k_bn_stats<<<STAT_B, 256, 0, stream>>>(h16b, partial);
  k_bn_finalize<<<1, 512, 0, stream>>>(partial, gamma0, beta0, scale, shift);

  // ----- layer 1 (BN0+ELU fused into GEMM1 A-staging) -----
  k_gemm1<<<dim3(GR, NHEAD), 256, 0, stream>>>(h16b, bt1, scale, shift, a_src1, a_dst1, h16a, s_src, s_dst);
  k_aggregate<<<GW, 256, 0, stream>>>(h16a, s_src, s_dst, off, csr, b1, h16b);
  k_bn_stats<<<STAT_B, 256, 0, stream>>>(h16b, partial);
  k_bn_finalize<<<1, 512, 0, stream>>>(partial, gamma1, beta1, scale, shift);

  // ----- classifier (BN1+ELU fused) -----
  k_final<<<GW, 256, 0, stream>>>(h16b, scale, shift, Wc, bc, out);
}

// Round 5
// 506.066 us; speedup vs baseline: 2.4809x; 1.0131x over previous
//
#include <hip/hip_runtime.h>
#include <hip/hip_bf16.h>
#include <math.h>
#include <stdint.h>

#define N_NODES 50000
#define N_EDGES 800000
#define E_TOT   (N_EDGES + N_NODES)   // 850000 with self loops
#define IN_CH   128
#define HID     64
#define NHEAD   8
#define C       512                   // NHEAD*HID
#define NEG_SLOPE 0.2f
#define BN_EPS    1e-5f
#define SM_EPS    1e-16f
#define SCAN_B    196                 // ceil(N_NODES/256)
#define STAT_B    256                 // bn_stats blocks

typedef __attribute__((ext_vector_type(8))) short bf16x8;
typedef __attribute__((ext_vector_type(4))) float f32x4;

__device__ __forceinline__ float lrelu(float x){ return x > 0.f ? x : NEG_SLOPE * x; }
__device__ __forceinline__ float elu(float x){ return x > 0.f ? x : __expf(x) - 1.f; }
__device__ __forceinline__ float bflo(unsigned u){ return __uint_as_float(u << 16); }
__device__ __forceinline__ float bfhi(unsigned u){ return __uint_as_float(u & 0xffff0000u); }
__device__ __forceinline__ float bfu(unsigned short u){ return __uint_as_float(((unsigned)u) << 16); }
__device__ __forceinline__ unsigned short f2bf(float f){
  unsigned u = __float_as_uint(f);
  unsigned r = u + 0x7fffu + ((u >> 16) & 1u);   // RNE
  return (unsigned short)(r >> 16);
}

// ---------------- edge dtype probe + extraction (+count fused) ----------------
__global__ void k_detect(const int* __restrict__ ei, int* flag){
  if (threadIdx.x == 0 && blockIdx.x == 0) {
    int f = 1;
    for (int i = 0; i < 32; i++) if (ei[2*i + 1] != 0) f = 0;  // int64 => high words 0
    *flag = f;
  }
}
__global__ void k_init_counts(int* counts){
  int i = blockIdx.x * 256 + threadIdx.x;
  if (i < N_NODES) counts[i] = 1;            // self loop
}
__global__ void k_extract_count(const int* __restrict__ ei, const int* __restrict__ flag,
                                int* __restrict__ src32, int* __restrict__ dst32,
                                int* counts){
  int e = blockIdx.x * 256 + threadIdx.x;
  if (e >= N_EDGES) return;
  int s, d;
  if (*flag) {
    const long long* e64 = (const long long*)ei;
    s = (int)e64[e];
    d = (int)e64[(size_t)N_EDGES + e];
  } else {
    s = ei[e];
    d = ei[N_EDGES + e];
  }
  src32[e] = s; dst32[e] = d;
  atomicAdd(&counts[d], 1);
}

// ---------------- multi-block exclusive scan ----------------
__global__ void k_scan1(const int* __restrict__ counts, int* __restrict__ excl, int* __restrict__ bsum){
  __shared__ int s[256];
  int tid = threadIdx.x;
  int i = blockIdx.x * 256 + tid;
  int v = (i < N_NODES) ? counts[i] : 0;
  s[tid] = v; __syncthreads();
#pragma unroll
  for (int d = 1; d < 256; d <<= 1) {
    int t = (tid >= d) ? s[tid - d] : 0;
    __syncthreads(); s[tid] += t; __syncthreads();
  }
  if (i < N_NODES) excl[i] = s[tid] - v;
  if (tid == 255) bsum[blockIdx.x] = s[255];
}
__global__ void k_scan2(int* bsum){
  __shared__ int s[256];
  int tid = threadIdx.x;
  int v = (tid < SCAN_B) ? bsum[tid] : 0;
  s[tid] = v; __syncthreads();
#pragma unroll
  for (int d = 1; d < 256; d <<= 1) {
    int t = (tid >= d) ? s[tid - d] : 0;
    __syncthreads(); s[tid] += t; __syncthreads();
  }
  if (tid < SCAN_B) bsum[tid] = s[tid] - v;
}
// scan3 also places the self-loop at off[i] and starts cursor past it
__global__ void k_scan3(const int* __restrict__ excl, const int* __restrict__ bsum,
                        int* __restrict__ off, int* __restrict__ cursor, int* __restrict__ csr){
  int i = blockIdx.x * 256 + threadIdx.x;
  if (i < N_NODES) {
    int o = excl[i] + bsum[blockIdx.x];
    off[i] = o; cursor[i] = o + 1; csr[o] = i;
  }
  if (i == 0) off[N_NODES] = E_TOT;
}
__global__ void k_scatter_edges(const int* __restrict__ src, const int* __restrict__ dst,
                                int* cursor, int* __restrict__ csr_src){
  int e = blockIdx.x * 256 + threadIdx.x;
  if (e < N_EDGES) { int d = dst[e]; int p = atomicAdd(&cursor[d], 1); csr_src[p] = src[e]; }
}

// ---------------- W -> bf16 transposed [h][c][k] ----------------
template<int K>
__global__ void k_transpose_w(const float* __restrict__ W, unsigned short* __restrict__ Bt){
  int i = blockIdx.x * 256 + threadIdx.x;     // out index, grid covers 8*64*K
  int k = i % K; int rem = i / K; int c = rem & 63; int h = rem >> 6;
  Bt[i] = f2bf(W[((size_t)h * K + k) * 64 + c]);
}

// ---------------- MFMA GEMM0: X[N,128]fp32 @ W0 (all 8 heads per block) ----------------
__global__ __launch_bounds__(256) void k_gemm0(const float* __restrict__ X,
                                               const unsigned short* __restrict__ Bt,   // [h][64][128]
                                               const float* __restrict__ a_src,
                                               const float* __restrict__ a_dst,
                                               unsigned short* __restrict__ H16,
                                               float* __restrict__ s_src,
                                               float* __restrict__ s_dst){
  __shared__ unsigned short LA[64 * 136];   // [row][k], staged ONCE for all 8 heads
  __shared__ unsigned short LB[64 * 136];   // [col][k], re-staged per head
  int r0 = blockIdx.x * 64;
  int tid = threadIdx.x;
  // stage A: fp32 -> bf16 in-flight
#pragma unroll
  for (int i = 0; i < 4; i++) {
    int idx = tid + i * 256;
    int r = idx >> 4, l16 = idx & 15;
    float4 u0 = make_float4(0.f,0.f,0.f,0.f), u1 = u0;
    if (r0 + r < N_NODES) {
      const float* xp = &X[(size_t)(r0 + r) * IN_CH + l16 * 8];
      u0 = *reinterpret_cast<const float4*>(xp);
      u1 = *reinterpret_cast<const float4*>(xp + 4);
    }
    ushort4 p0, p1;
    p0.x = f2bf(u0.x); p0.y = f2bf(u0.y); p0.z = f2bf(u0.z); p0.w = f2bf(u0.w);
    p1.x = f2bf(u1.x); p1.y = f2bf(u1.y); p1.z = f2bf(u1.z); p1.w = f2bf(u1.w);
    *reinterpret_cast<ushort4*>(&LA[r * 136 + l16 * 8]) = p0;
    *reinterpret_cast<ushort4*>(&LA[r * 136 + l16 * 8 + 4]) = p1;
  }
  int w = tid >> 6, l = tid & 63;
  int lr = l & 15, lg = l >> 4;
  for (int h = 0; h < NHEAD; h++) {
    __syncthreads();   // first iter: A staged; later iters: protect LB reuse
#pragma unroll
    for (int i = 0; i < 4; i++) {
      int idx = tid + i * 256;
      int c = idx >> 4, l16 = idx & 15;
      uint4 v = *reinterpret_cast<const uint4*>(&Bt[(size_t)h * 8192 + c * 128 + l16 * 8]);
      *reinterpret_cast<uint4*>(&LB[c * 136 + l16 * 8]) = v;
    }
    __syncthreads();
    f32x4 acc[4] = {};
#pragma unroll
    for (int kf = 0; kf < 4; kf++) {
      bf16x8 af = *reinterpret_cast<const bf16x8*>(&LA[(w * 16 + lr) * 136 + kf * 32 + lg * 8]);
#pragma unroll
      for (int cf = 0; cf < 4; cf++) {
        bf16x8 bfr = *reinterpret_cast<const bf16x8*>(&LB[(cf * 16 + lr) * 136 + kf * 32 + lg * 8]);
        acc[cf] = __builtin_amdgcn_mfma_f32_16x16x32_bf16(af, bfr, acc[cf], 0, 0, 0);
      }
    }
#pragma unroll
    for (int cf = 0; cf < 4; cf++)
#pragma unroll
      for (int rr = 0; rr < 4; rr++) {
        int gr = r0 + w * 16 + lg * 4 + rr;
        if (gr < N_NODES)
          H16[(size_t)gr * C + h * HID + cf * 16 + lr] = f2bf(acc[cf][rr]);
      }
    float ps[4] = {}, pd[4] = {};
#pragma unroll
    for (int cf = 0; cf < 4; cf++) {
      float as_ = a_src[h * HID + cf * 16 + lr];
      float ad_ = a_dst[h * HID + cf * 16 + lr];
#pragma unroll
      for (int rr = 0; rr < 4; rr++) { ps[rr] += acc[cf][rr] * as_; pd[rr] += acc[cf][rr] * ad_; }
    }
#pragma unroll
    for (int rr = 0; rr < 4; rr++)
#pragma unroll
      for (int o = 1; o < 16; o <<= 1) { ps[rr] += __shfl_xor(ps[rr], o, 64); pd[rr] += __shfl_xor(pd[rr], o, 64); }
    if (lr == 0) {
#pragma unroll
      for (int rr = 0; rr < 4; rr++) {
        int gr = r0 + w * 16 + lg * 4 + rr;
        if (gr < N_NODES) { s_src[gr * NHEAD + h] = ps[rr]; s_dst[gr * NHEAD + h] = pd[rr]; }
      }
    }
  }
}

// ---------------- MFMA GEMM1: elu(bn(Hprev bf16)) @ W1 -> H16 bf16 + s scores ----------------
__global__ __launch_bounds__(256) void k_gemm1(const unsigned short* __restrict__ Hb,
                                               const unsigned short* __restrict__ Bt,   // [h][64][64]
                                               const float* __restrict__ scale,
                                               const float* __restrict__ shift,
                                               const float* __restrict__ a_src,
                                               const float* __restrict__ a_dst,
                                               unsigned short* __restrict__ H16,
                                               float* __restrict__ s_src,
                                               float* __restrict__ s_dst){
  __shared__ unsigned short LA[64 * 72];    // [row][k], row stride 144B
  __shared__ unsigned short LB[64 * 72];
  int r0 = blockIdx.x * 64, h = blockIdx.y;
  int tid = threadIdx.x;
#pragma unroll
  for (int i = 0; i < 4; i++) {
    int idx = tid + i * 256;
    int r = idx >> 4, l16 = idx & 15;
    ushort4 hv = make_ushort4(0, 0, 0, 0);
    if (r0 + r < N_NODES)
      hv = *reinterpret_cast<const ushort4*>(&Hb[(size_t)(r0 + r) * C + h * HID + l16 * 4]);
    float4 sc = *reinterpret_cast<const float4*>(&scale[h * HID + l16 * 4]);
    float4 sh = *reinterpret_cast<const float4*>(&shift[h * HID + l16 * 4]);
    ushort4 p;
    p.x = f2bf(elu(sc.x * bfu(hv.x) + sh.x));
    p.y = f2bf(elu(sc.y * bfu(hv.y) + sh.y));
    p.z = f2bf(elu(sc.z * bfu(hv.z) + sh.z));
    p.w = f2bf(elu(sc.w * bfu(hv.w) + sh.w));
    *reinterpret_cast<ushort4*>(&LA[r * 72 + l16 * 4]) = p;
  }
#pragma unroll
  for (int i = 0; i < 2; i++) {
    int idx = tid + i * 256;
    int c = idx >> 3, l8 = idx & 7;
    uint4 v = *reinterpret_cast<const uint4*>(&Bt[(size_t)h * 4096 + c * 64 + l8 * 8]);
    *reinterpret_cast<uint4*>(&LB[c * 72 + l8 * 8]) = v;
  }
  __syncthreads();
  int w = tid >> 6, l = tid & 63;
  int lr = l & 15, lg = l >> 4;
  f32x4 acc[4] = {};
#pragma unroll
  for (int kf = 0; kf < 2; kf++) {
    bf16x8 af = *reinterpret_cast<const bf16x8*>(&LA[(w * 16 + lr) * 72 + kf * 32 + lg * 8]);
#pragma unroll
    for (int cf = 0; cf < 4; cf++) {
      bf16x8 bfr = *reinterpret_cast<const bf16x8*>(&LB[(cf * 16 + lr) * 72 + kf * 32 + lg * 8]);
      acc[cf] = __builtin_amdgcn_mfma_f32_16x16x32_bf16(af, bfr, acc[cf], 0, 0, 0);
    }
  }
#pragma unroll
  for (int cf = 0; cf < 4; cf++)
#pragma unroll
    for (int rr = 0; rr < 4; rr++) {
      int gr = r0 + w * 16 + lg * 4 + rr;
      if (gr < N_NODES)
        H16[(size_t)gr * C + h * HID + cf * 16 + lr] = f2bf(acc[cf][rr]);
    }
  float ps[4] = {}, pd[4] = {};
#pragma unroll
  for (int cf = 0; cf < 4; cf++) {
    float as_ = a_src[h * HID + cf * 16 + lr];
    float ad_ = a_dst[h * HID + cf * 16 + lr];
#pragma unroll
    for (int rr = 0; rr < 4; rr++) { ps[rr] += acc[cf][rr] * as_; pd[rr] += acc[cf][rr] * ad_; }
  }
#pragma unroll
  for (int rr = 0; rr < 4; rr++)
#pragma unroll
    for (int o = 1; o < 16; o <<= 1) { ps[rr] += __shfl_xor(ps[rr], o, 64); pd[rr] += __shfl_xor(pd[rr], o, 64); }
  if (lr == 0) {
#pragma unroll
    for (int rr = 0; rr < 4; rr++) {
      int gr = r0 + w * 16 + lg * 4 + rr;
      if (gr < N_NODES) { s_src[gr * NHEAD + h] = ps[rr]; s_dst[gr * NHEAD + h] = pd[rr]; }
    }
  }
}

// ---------------- single-pass softmax + aggregation (1 wave / node, bf16 in/out) ----------------
// LDS-staged indices + 4-deep unrolled gather for memory-level parallelism.
__global__ __launch_bounds__(256) void k_aggregate(const unsigned short* __restrict__ H16,
                                                   const float* __restrict__ s_src,
                                                   const float* __restrict__ s_dst,
                                                   const int* __restrict__ off,
                                                   const int* __restrict__ csr,
                                                   const float* __restrict__ bias,
                                                   unsigned short* __restrict__ HoutB){
  __shared__ float aexp[4][64][8];
  __shared__ int   sidx[4][64];
  int wv = threadIdx.x >> 6, lane = threadIdx.x & 63;
  int n = blockIdx.x * 4 + wv;
  if (n >= N_NODES) return;
  int e0 = off[n], deg = off[n + 1] - e0;
  int hsel = lane >> 3;

  float sd[NHEAD];
#pragma unroll
  for (int h = 0; h < NHEAD; h++) sd[h] = s_dst[n * NHEAD + h];

  float acc[8] = {};
  float dnl[NHEAD] = {};

  for (int base = 0; base < deg; base += 64) {
    int e = base + lane;
    int cnt = min(64, deg - base);
    if (e < deg) {
      int s = csr[e0 + e];
      sidx[wv][lane] = s;
      const float4* sp = reinterpret_cast<const float4*>(&s_src[s * NHEAD]);
      float4 s01 = sp[0], s23 = sp[1];
      float sv[8] = { s01.x, s01.y, s01.z, s01.w, s23.x, s23.y, s23.z, s23.w };
#pragma unroll
      for (int h = 0; h < NHEAD; h++) {
        float ex = __expf(lrelu(sv[h] + sd[h]));
        dnl[h] += ex;
        aexp[wv][lane][h] = ex;
      }
    }
    // wave-local LDS (no cross-wave sharing): compiler inserts lgkmcnt waits
    int j = 0;
    for (; j + 4 <= cnt; j += 4) {
      int s0 = sidx[wv][j+0], s1 = sidx[wv][j+1], s2 = sidx[wv][j+2], s3 = sidx[wv][j+3];
      float a0 = aexp[wv][j+0][hsel], a1 = aexp[wv][j+1][hsel];
      float a2 = aexp[wv][j+2][hsel], a3 = aexp[wv][j+3][hsel];
      uint4 v0 = reinterpret_cast<const uint4*>(H16 + (size_t)s0 * C)[lane];
      uint4 v1 = reinterpret_cast<const uint4*>(H16 + (size_t)s1 * C)[lane];
      uint4 v2 = reinterpret_cast<const uint4*>(H16 + (size_t)s2 * C)[lane];
      uint4 v3 = reinterpret_cast<const uint4*>(H16 + (size_t)s3 * C)[lane];
      acc[0] += a0 * bflo(v0.x); acc[1] += a0 * bfhi(v0.x);
      acc[2] += a0 * bflo(v0.y); acc[3] += a0 * bfhi(v0.y);
      acc[4] += a0 * bflo(v0.z); acc[5] += a0 * bfhi(v0.z);
      acc[6] += a0 * bflo(v0.w); acc[7] += a0 * bfhi(v0.w);
      acc[0] += a1 * bflo(v1.x); acc[1] += a1 * bfhi(v1.x);
      acc[2] += a1 * bflo(v1.y); acc[3] += a1 * bfhi(v1.y);
      acc[4] += a1 * bflo(v1.z); acc[5] += a1 * bfhi(v1.z);
      acc[6] += a1 * bflo(v1.w); acc[7] += a1 * bfhi(v1.w);
      acc[0] += a2 * bflo(v2.x); acc[1] += a2 * bfhi(v2.x);
      acc[2] += a2 * bflo(v2.y); acc[3] += a2 * bfhi(v2.y);
      acc[4] += a2 * bflo(v2.z); acc[5] += a2 * bfhi(v2.z);
      acc[6] += a2 * bflo(v2.w); acc[7] += a2 * bfhi(v2.w);
      acc[0] += a3 * bflo(v3.x); acc[1] += a3 * bfhi(v3.x);
      acc[2] += a3 * bflo(v3.y); acc[3] += a3 * bfhi(v3.y);
      acc[4] += a3 * bflo(v3.z); acc[5] += a3 * bfhi(v3.z);
      acc[6] += a3 * bflo(v3.w); acc[7] += a3 * bfhi(v3.w);
    }
    for (; j < cnt; j++) {
      int s = sidx[wv][j];
      float a = aexp[wv][j][hsel];
      uint4 v = reinterpret_cast<const uint4*>(H16 + (size_t)s * C)[lane];
      acc[0] += a * bflo(v.x); acc[1] += a * bfhi(v.x);
      acc[2] += a * bflo(v.y); acc[3] += a * bfhi(v.y);
      acc[4] += a * bflo(v.z); acc[5] += a * bfhi(v.z);
      acc[6] += a * bflo(v.w); acc[7] += a * bfhi(v.w);
    }
  }

  float mydn = 0.f;
#pragma unroll
  for (int h = 0; h < NHEAD; h++) {
    float d = dnl[h];
#pragma unroll
    for (int o = 32; o; o >>= 1) d += __shfl_xor(d, o, 64);
    if (hsel == h) mydn = d;
  }
  float inv = 1.f / (mydn + SM_EPS);

  const float* bp = bias + lane * 8;
  ushort4 p0, p1;
  p0.x = f2bf(acc[0]*inv + bp[0]); p0.y = f2bf(acc[1]*inv + bp[1]);
  p0.z = f2bf(acc[2]*inv + bp[2]); p0.w = f2bf(acc[3]*inv + bp[3]);
  p1.x = f2bf(acc[4]*inv + bp[4]); p1.y = f2bf(acc[5]*inv + bp[5]);
  p1.z = f2bf(acc[6]*inv + bp[6]); p1.w = f2bf(acc[7]*inv + bp[7]);
  unsigned short* op = HoutB + (size_t)n * C + lane * 8;
  *reinterpret_cast<ushort4*>(op) = p0;
  *reinterpret_cast<ushort4*>(op + 4) = p1;
}

// ---------------- BatchNorm stats: per-block partials (no atomics) ----------------
__global__ __launch_bounds__(256) void k_bn_stats(const unsigned short* __restrict__ Hb,
                                                  float* __restrict__ partial){
  __shared__ float red[4][64][16];
  int tid = threadIdx.x, w = tid >> 6, c64 = tid & 63;
  float s[8] = {}, q[8] = {};
  for (int r = blockIdx.x * 4 + w; r < N_NODES; r += gridDim.x * 4) {
    uint4 v = *reinterpret_cast<const uint4*>(&Hb[(size_t)r * C + c64 * 8]);
    float f[8] = { bflo(v.x), bfhi(v.x), bflo(v.y), bfhi(v.y),
                   bflo(v.z), bfhi(v.z), bflo(v.w), bfhi(v.w) };
#pragma unroll
    for (int k = 0; k < 8; k++) { s[k] += f[k]; q[k] += f[k] * f[k]; }
  }
#pragma unroll
  for (int k = 0; k < 8; k++) { red[w][c64][k] = s[k]; red[w][c64][k + 8] = q[k]; }
  __syncthreads();
  if (w == 0) {
#pragma unroll
    for (int k = 0; k < 8; k++) {
      float ss = red[0][c64][k] + red[1][c64][k] + red[2][c64][k] + red[3][c64][k];
      float qq = red[0][c64][k+8] + red[1][c64][k+8] + red[2][c64][k+8] + red[3][c64][k+8];
      partial[(size_t)blockIdx.x * 1024 + c64 * 8 + k] = ss;
      partial[(size_t)blockIdx.x * 1024 + 512 + c64 * 8 + k] = qq;
    }
  }
}
__global__ void k_bn_finalize(const float* __restrict__ partial, const float* __restrict__ gamma,
                              const float* __restrict__ beta, float* __restrict__ scale,
                              float* __restrict__ shift){
  int c = threadIdx.x;  // 512 threads
  float s = 0.f, q = 0.f;
  for (int b = 0; b < STAT_B; b++) {
    s += partial[(size_t)b * 1024 + c];
    q += partial[(size_t)b * 1024 + 512 + c];
  }
  float mean = s * (1.f / N_NODES);
  float var  = q * (1.f / N_NODES) - mean * mean;
  float sc = gamma[c] * rsqrtf(var + BN_EPS);
  scale[c] = sc;
  shift[c] = beta[c] - mean * sc;
}

// ---------------- final: out = elu(bn(Hb)) @ Wc + bc ----------------
__global__ __launch_bounds__(256) void k_final(const unsigned short* __restrict__ Hb,
                                               const float* __restrict__ scale,
                                               const float* __restrict__ shift,
                                               const float* __restrict__ Wc,
                                               const float* __restrict__ bc,
                                               float* __restrict__ out){
  int wave = threadIdx.x >> 6, lane = threadIdx.x & 63;
  int n = blockIdx.x * 4 + wave;
  if (n >= N_NODES) return;
  uint4 v = *reinterpret_cast<const uint4*>(&Hb[(size_t)n * C + lane * 8]);
  float f[8] = { bflo(v.x), bfhi(v.x), bflo(v.y), bfhi(v.y),
                 bflo(v.z), bfhi(v.z), bflo(v.w), bfhi(v.w) };
  float4 sc0 = *reinterpret_cast<const float4*>(&scale[lane * 8]);
  float4 sc1 = *reinterpret_cast<const float4*>(&scale[lane * 8 + 4]);
  float4 sh0 = *reinterpret_cast<const float4*>(&shift[lane * 8]);
  float4 sh1 = *reinterpret_cast<const float4*>(&shift[lane * 8 + 4]);
  float scv[8] = { sc0.x, sc0.y, sc0.z, sc0.w, sc1.x, sc1.y, sc1.z, sc1.w };
  float shv[8] = { sh0.x, sh0.y, sh0.z, sh0.w, sh1.x, sh1.y, sh1.z, sh1.w };
  float a0 = 0.f, a1 = 0.f;
#pragma unroll
  for (int k = 0; k < 8; k++) {
    float t = elu(scv[k] * f[k] + shv[k]);
    int ch = lane * 8 + k;
    a0 += t * Wc[ch * 2 + 0];
    a1 += t * Wc[ch * 2 + 1];
  }
#pragma unroll
  for (int o = 32; o; o >>= 1) { a0 += __shfl_xor(a0, o, 64); a1 += __shfl_xor(a1, o, 64); }
  if (lane == 0) { out[n * 2 + 0] = a0 + bc[0]; out[n * 2 + 1] = a1 + bc[1]; }
}

extern "C" void kernel_launch(void* const* d_in, const int* in_sizes, int n_in,
                              void* d_out, int out_size, void* d_ws, size_t ws_size,
                              hipStream_t stream) {
  const float* x      = (const float*)d_in[0];
  const int*   ei     = (const int*)d_in[1];
  const float* W0     = (const float*)d_in[2];
  const float* a_src0 = (const float*)d_in[3];
  const float* a_dst0 = (const float*)d_in[4];
  const float* b0     = (const float*)d_in[5];
  const float* gamma0 = (const float*)d_in[6];
  const float* beta0  = (const float*)d_in[7];
  const float* W1     = (const float*)d_in[8];
  const float* a_src1 = (const float*)d_in[9];
  const float* a_dst1 = (const float*)d_in[10];
  const float* b1     = (const float*)d_in[11];
  const float* gamma1 = (const float*)d_in[12];
  const float* beta1  = (const float*)d_in[13];
  const float* Wc     = (const float*)d_in[14];
  const float* bc     = (const float*)d_in[15];
  float* out = (float*)d_out;

  char* ws = (char*)d_ws;
  size_t o = 0;
  auto alloc = [&](size_t bytes) { char* p = ws + o; o = (o + bytes + 255) & ~(size_t)255; return p; };
  int*   flag    = (int*)  alloc(4);
  int*   src32   = (int*)  alloc((size_t)N_EDGES * 4);
  int*   dst32   = (int*)  alloc((size_t)N_EDGES * 4);
  int*   counts  = (int*)  alloc((size_t)N_NODES * 4);
  int*   excl    = (int*)  alloc((size_t)N_NODES * 4);
  int*   bsum    = (int*)  alloc(256 * 4);
  int*   off     = (int*)  alloc((size_t)(N_NODES + 1) * 4);
  int*   cursor  = (int*)  alloc((size_t)N_NODES * 4);
  int*   csr     = (int*)  alloc((size_t)E_TOT * 4);
  float* s_src   = (float*)alloc((size_t)N_NODES * NHEAD * 4);
  float* s_dst   = (float*)alloc((size_t)N_NODES * NHEAD * 4);
  float* partial = (float*)alloc((size_t)STAT_B * 1024 * 4);
  float* scale   = (float*)alloc(C * 4);
  float* shift   = (float*)alloc(C * 4);
  unsigned short* bt0  = (unsigned short*)alloc((size_t)NHEAD * HID * IN_CH * 2);
  unsigned short* bt1  = (unsigned short*)alloc((size_t)NHEAD * HID * HID * 2);
  unsigned short* h16a = (unsigned short*)alloc((size_t)N_NODES * C * 2);
  unsigned short* h16b = (unsigned short*)alloc((size_t)N_NODES * C * 2);

  const int GE = (N_EDGES + 255) / 256;      // 3125
  const int GN = (N_NODES + 255) / 256;      // 196
  const int GW = (N_NODES + 3) / 4;          // 12500
  const int GR = (N_NODES + 63) / 64;        // 782

  // edges -> int32 + degree counts, CSR by dst (with self loops)
  k_detect<<<1, 64, 0, stream>>>(ei, flag);
  k_init_counts<<<GN, 256, 0, stream>>>(counts);
  k_extract_count<<<GE, 256, 0, stream>>>(ei, flag, src32, dst32, counts);

  // weight prep (independent of CSR chain)
  k_transpose_w<IN_CH><<<(NHEAD * HID * IN_CH + 255) / 256, 256, 0, stream>>>(W0, bt0);
  k_transpose_w<HID><<<(NHEAD * HID * HID + 255) / 256, 256, 0, stream>>>(W1, bt1);

  k_scan1<<<GN, 256, 0, stream>>>(counts, excl, bsum);
  k_scan2<<<1, 256, 0, stream>>>(bsum);
  k_scan3<<<GN, 256, 0, stream>>>(excl, bsum, off, cursor, csr);
  k_scatter_edges<<<GE, 256, 0, stream>>>(src32, dst32, cursor, csr);

  // ----- layer 0 -----
  k_gemm0<<<GR, 256, 0, stream>>>(x, bt0, a_src0, a_dst0, h16a, s_src, s_dst);
  k_aggregate<<<GW, 256, 0, stream>>>(h16a, s_src, s_dst, off, csr, b0, h16b);
  k_bn_stats<<<STAT_B, 256, 0, stream>>>(h16b, partial);
  k_bn_finalize<<<1, 512, 0, stream>>>(partial, gamma0, beta0, scale, shift);

  // ----- layer 1 (BN0+ELU fused into GEMM1 A-staging) -----
  k_gemm1<<<dim3(GR, NHEAD), 256, 0, stream>>>(h16b, bt1, scale, shift, a_src1, a_dst1, h16a, s_src, s_dst);
  k_aggregate<<<GW, 256, 0, stream>>>(h16a, s_src, s_dst, off, csr, b1, h16b);
  k_bn_stats<<<STAT_B, 256, 0, stream>>>(h16b, partial);
  k_bn_finalize<<<1, 512, 0, stream>>>(partial, gamma1, beta1, scale, shift);

  // ----- classifier (BN1+ELU fused) -----
  k_final<<<GW, 256, 0, stream>>>(h16b, scale, shift, Wc, bc, out);
}